// Round 16
// baseline (130.868 us; speedup 1.0000x reference)
//
#include <hip/hip_runtime.h>

#define B_    1024
#define G_    512
#define K_    128
#define J_    129
#define JP_   132       /* padded j-stride inside W2/R blocks (8B-aligned pairs) */
#define E2_   128
#define KK_   16512     /* K_*J_  (tables sq2/cross layout) */
#define KK2_  16896     /* K_*JP_ (W2/R block region) */
#define KKE2_ 17024     /* KK2_ + K_ (appended wimg columns) */
#define KKP_  17408     /* padded: SPLITS*KCHUNK */
#define SPLITS 16
#define KCHUNK 1088     /* KKP_/SPLITS */
#define BK_   64
#define KSTEPS 17       /* KCHUNK/BK_ */
#define GS_   16        /* g-splits for table partials */

using short8 = __attribute__((ext_vector_type(8))) short;
using f32x4  = __attribute__((ext_vector_type(4))) float;

__device__ __forceinline__ float bf2f(unsigned short h){
  return __uint_as_float(((unsigned int)h) << 16);
}
__device__ __forceinline__ unsigned short f2bf(float f){
  unsigned int u = __float_as_uint(f);
  u += 0x7fffu + ((u >> 16) & 1u);          // round-to-nearest-even
  return (unsigned short)(u >> 16);
}

#define GLOAD16(gptr, ldst) __builtin_amdgcn_global_load_lds( \
    (const __attribute__((address_space(1))) unsigned int*)(gptr), \
    (__attribute__((address_space(3))) unsigned int*)(ldst), 16, 0, 0)

// ---- dual-b block reductions (512 thr, 8 waves); red buffers sized [16] ----
__device__ __forceinline__ void blockSoftmaxMS2(float x0, float x1, bool act,
    float* redm, float* reds, int t,
    float& m0o, float& s0o, float& m1o, float& s1o){
  float m0 = x0, s0 = act ? 1.f : 0.f;
  float m1 = x1, s1 = act ? 1.f : 0.f;
  #pragma unroll
  for (int off = 32; off > 0; off >>= 1){
    float om0 = __shfl_down(m0, off), os0 = __shfl_down(s0, off);
    float om1 = __shfl_down(m1, off), os1 = __shfl_down(s1, off);
    float nm0 = fmaxf(m0, om0);
    s0 = s0*__expf(m0 - nm0) + os0*__expf(om0 - nm0); m0 = nm0;
    float nm1 = fmaxf(m1, om1);
    s1 = s1*__expf(m1 - nm1) + os1*__expf(om1 - nm1); m1 = nm1;
  }
  __syncthreads();
  if ((t & 63) == 0){
    redm[t >> 6] = m0; reds[t >> 6] = s0;
    redm[8 + (t >> 6)] = m1; reds[8 + (t >> 6)] = s1;
  }
  __syncthreads();
  float gm0 = redm[0], gs0 = reds[0], gm1 = redm[8], gs1 = reds[8];
  #pragma unroll
  for (int w = 1; w < 8; w++){
    float om0 = redm[w], os0 = reds[w];
    float nm0 = fmaxf(gm0, om0);
    gs0 = gs0*__expf(gm0 - nm0) + os0*__expf(om0 - nm0); gm0 = nm0;
    float om1 = redm[8 + w], os1 = reds[8 + w];
    float nm1 = fmaxf(gm1, om1);
    gs1 = gs1*__expf(gm1 - nm1) + os1*__expf(om1 - nm1); gm1 = nm1;
  }
  m0o = gm0; s0o = gs0; m1o = gm1; s1o = gs1;
}

__device__ __forceinline__ void blockSum2(float v0, float v1, float* red, int t,
                                          float& r0, float& r1){
  #pragma unroll
  for (int off = 32; off > 0; off >>= 1){
    v0 += __shfl_down(v0, off);
    v1 += __shfl_down(v1, off);
  }
  __syncthreads();
  if ((t & 63) == 0){ red[t >> 6] = v0; red[8 + (t >> 6)] = v1; }
  __syncthreads();
  r0 = ((red[0] + red[1]) + (red[2] + red[3])) + ((red[4] + red[5]) + (red[6] + red[7]));
  r1 = ((red[8] + red[9]) + (red[10] + red[11])) + ((red[12] + red[13]) + (red[14] + red[15]));
  __syncthreads();
}

__device__ __forceinline__ void blockSoftmaxMSI2(float x0, float x1, int idx, bool act,
    float* redm, float* reds, int* redi, int t,
    float& m0o, float& s0o, int& i0o, float& m1o, float& s1o, int& i1o){
  float m0 = x0, s0 = act ? 1.f : 0.f; int i0 = idx;
  float m1 = x1, s1 = act ? 1.f : 0.f; int i1 = idx;
  #pragma unroll
  for (int off = 32; off > 0; off >>= 1){
    float om0 = __shfl_down(m0, off), os0 = __shfl_down(s0, off);
    int   oi0 = __shfl_down(i0, off);
    float om1 = __shfl_down(m1, off), os1 = __shfl_down(s1, off);
    int   oi1 = __shfl_down(i1, off);
    bool tk0 = (om0 > m0) || (om0 == m0 && oi0 < i0);
    float nm0 = fmaxf(m0, om0);
    s0 = s0*__expf(m0 - nm0) + os0*__expf(om0 - nm0);
    i0 = tk0 ? oi0 : i0; m0 = nm0;
    bool tk1 = (om1 > m1) || (om1 == m1 && oi1 < i1);
    float nm1 = fmaxf(m1, om1);
    s1 = s1*__expf(m1 - nm1) + os1*__expf(om1 - nm1);
    i1 = tk1 ? oi1 : i1; m1 = nm1;
  }
  __syncthreads();
  if ((t & 63) == 0){
    redm[t >> 6] = m0; reds[t >> 6] = s0; redi[t >> 6] = i0;
    redm[8 + (t >> 6)] = m1; reds[8 + (t >> 6)] = s1; redi[8 + (t >> 6)] = i1;
  }
  __syncthreads();
  float gm0 = redm[0], gs0 = reds[0]; int gi0 = redi[0];
  float gm1 = redm[8], gs1 = reds[8]; int gi1 = redi[8];
  #pragma unroll
  for (int w = 1; w < 8; w++){
    { float om = redm[w], os = reds[w]; int oi = redi[w];
      bool tk = (om > gm0) || (om == gm0 && oi < gi0);
      float nm = fmaxf(gm0, om);
      gs0 = gs0*__expf(gm0 - nm) + os*__expf(om - nm);
      gi0 = tk ? oi : gi0; gm0 = nm; }
    { float om = redm[8 + w], os = reds[8 + w]; int oi = redi[8 + w];
      bool tk = (om > gm1) || (om == gm1 && oi < gi1);
      float nm = fmaxf(gm1, om);
      gs1 = gs1*__expf(gm1 - nm) + os*__expf(om - nm);
      gi1 = tk ? oi : gi1; gm1 = nm; }
  }
  m0o = gm0; s0o = gs0; i0o = gi0; m1o = gm1; s1o = gs1; i1o = gi1;
}

// ---- norms/transposes (0-4) + wimgT hi/lo (5) + W2 tail (6-69)
__global__ __launch_bounds__(1024) void norms_kernel(
    const float* __restrict__ wimg, const float* __restrict__ wrec,
    const float* __restrict__ wrec2, float* __restrict__ c1norm,
    float* __restrict__ w3norm, float* __restrict__ w6norm,
    float* __restrict__ wrecT, float* __restrict__ wrec2T,
    unsigned short* __restrict__ wThi, unsigned short* __restrict__ wTlo,
    unsigned short* __restrict__ W2){
  int t = threadIdx.x;
  if (blockIdx.x == 0){
    __shared__ float red[8][128];
    int k = t & 127, sl = t >> 7;
    float s = 0.f;
    int g0 = sl * (G_/8);
    for (int g = g0; g < g0 + G_/8; g++){
      float v = wimg[g*K_ + k]; s += v*v;
    }
    red[sl][k] = s;
    __syncthreads();
    if (t < 128){
      float r = 0.f;
      #pragma unroll
      for (int i = 0; i < 8; i++) r += red[i][t];
      c1norm[t] = r;
    }
  } else if (blockIdx.x == 1){
    int wave = t >> 6, lane = t & 63;
    for (int k = wave; k < K_; k += 16){
      float v0 = wrec[k*E2_ + lane], v1 = wrec[k*E2_ + 64 + lane];
      float s = v0*v0 + v1*v1;
      #pragma unroll
      for (int off = 32; off > 0; off >>= 1) s += __shfl_down(s, off);
      if (lane == 0) w3norm[k] = s;
    }
  } else if (blockIdx.x == 2){
    int wave = t >> 6, lane = t & 63;
    for (int j = wave; j < J_; j += 16){
      float v0 = wrec2[j*E2_ + lane], v1 = wrec2[j*E2_ + 64 + lane];
      float s = v0*v0 + v1*v1;
      #pragma unroll
      for (int off = 32; off > 0; off >>= 1) s += __shfl_down(s, off);
      if (lane == 0) w6norm[j] = s;
    }
  } else if (blockIdx.x == 3){
    for (int n = t; n < K_*E2_; n += 1024){
      int k = n >> 7, e = n & 127;
      wrecT[e*K_ + k] = wrec[n];
    }
  } else if (blockIdx.x == 4){
    for (int n = t; n < J_*E2_; n += 1024){
      int j = n >> 7, e = n & 127;
      wrec2T[e*J_ + j] = wrec2[n];
    }
  } else if (blockIdx.x == 5){
    // wimgT hi/lo bf16: [k][g], n = k*512+g
    for (int n = t; n < K_*G_; n += 1024){
      int k = n >> 9, g = n & 511;
      float v = wimg[g*K_ + k];
      unsigned short h = f2bf(v);
      wThi[n] = h;
      wTlo[n] = f2bf(v - bf2f(h));
    }
  } else {
    // W2 tail for 8 g's: appended wimg cols, zero pads, zero j={129,130,131}
    int g = (blockIdx.x - 6) * 8 + (t >> 7);
    int col = t & 127;
    unsigned short* dst = W2 + (size_t)g * KKP_;
    dst[KK2_ + col]        = f2bf(wimg[g*K_ + col]);
    dst[KKE2_ + col]       = 0;
    dst[KKE2_ + 128 + col] = 0;
    dst[KKE2_ + 256 + col] = 0;
    dst[col*JP_ + 129] = 0;
    dst[col*JP_ + 130] = 0;
    dst[col*JP_ + 131] = 0;
  }
}

// ---- img hi/lo bf16 split + imgnorm[b]
__global__ __launch_bounds__(128) void splitimg_kernel(
    const float* __restrict__ img, unsigned short* __restrict__ ihi,
    unsigned short* __restrict__ ilo, float* __restrict__ inorm){
  __shared__ float redf[2];
  int b = blockIdx.x, t = threadIdx.x;
  float acc = 0.f;
  #pragma unroll
  for (int i = 0; i < 4; i++){
    int g = t + 128*i;
    float v = img[b*G_ + g];
    unsigned short h = f2bf(v);
    ihi[b*G_ + g] = h;
    ilo[b*G_ + g] = f2bf(v - bf2f(h));
    acc += v*v;
  }
  #pragma unroll
  for (int off = 32; off > 0; off >>= 1) acc += __shfl_down(acc, off);
  if ((t & 63) == 0) redf[t >> 6] = acc;
  __syncthreads();
  if (t == 0) inorm[b] = redf[0] + redf[1];
}

// ---- D1[b,k] = sum_g img[b,g]*wimg[g,k], compensated bf16 MFMA, split-K=4
__global__ __launch_bounds__(256) void d1gemm_kernel(
    const unsigned short* __restrict__ ihi, const unsigned short* __restrict__ ilo,
    const unsigned short* __restrict__ wThi, const unsigned short* __restrict__ wTlo,
    float* __restrict__ D1p){
  __shared__ __align__(16) unsigned int lds[16384];  // Ahi,Alo,Bhi,Blo x 4096u
  auto lds3 = (__attribute__((address_space(3))) unsigned int*)lds;
  int tid = threadIdx.x;
  int l = tid & 63;
  int wv = tid >> 6;
  int wr = (wv >> 1) * 64, wc = (wv & 1) * 64;
  int b0 = blockIdx.x * 128;
  int gb = blockIdx.y * 128;        // K-split base

  int srow = tid >> 3;
  int cswz = (tid & 7) ^ (srow & 7);
  const unsigned short* gah = ihi  + (size_t)(b0 + srow)*G_ + gb + cswz*8;
  const unsigned short* gal = ilo  + (size_t)(b0 + srow)*G_ + gb + cswz*8;
  const unsigned short* gbh = wThi + (size_t)srow*G_ + gb + cswz*8;
  const unsigned short* gbl = wTlo + (size_t)srow*G_ + gb + cswz*8;

  int lrow = l & 15, lh = l >> 4, p7 = l & 7;

  f32x4 zero4 = {0.f, 0.f, 0.f, 0.f};
  f32x4 acc[4][4];
  #pragma unroll
  for (int mi = 0; mi < 4; mi++)
    #pragma unroll
    for (int ni = 0; ni < 4; ni++) acc[mi][ni] = zero4;

  for (int ks = 0; ks < 2; ks++){
    __syncthreads();                      // prior reads done
    #pragma unroll
    for (int c = 0; c < 4; c++){
      GLOAD16(gah + (size_t)c*32*G_, lds3 +         c*1024 + wv*256);
      GLOAD16(gal + (size_t)c*32*G_, lds3 + 4096  + c*1024 + wv*256);
      GLOAD16(gbh + (size_t)c*32*G_, lds3 + 8192  + c*1024 + wv*256);
      GLOAD16(gbl + (size_t)c*32*G_, lds3 + 12288 + c*1024 + wv*256);
    }
    gah += BK_; gal += BK_; gbh += BK_; gbl += BK_;
    __syncthreads();                      // drain
    #pragma unroll
    for (int s2 = 0; s2 < 2; s2++){
      int slot = ((s2 << 2) + lh) ^ p7;
      short8 ah[4], al[4], bh[4], bl[4];
      #pragma unroll
      for (int mi = 0; mi < 4; mi++){
        ah[mi] = *(const short8*)(lds +         (wr + mi*16 + lrow)*32 + slot*4);
        al[mi] = *(const short8*)(lds + 4096  + (wr + mi*16 + lrow)*32 + slot*4);
      }
      #pragma unroll
      for (int ni = 0; ni < 4; ni++){
        bh[ni] = *(const short8*)(lds + 8192  + (wc + ni*16 + lrow)*32 + slot*4);
        bl[ni] = *(const short8*)(lds + 12288 + (wc + ni*16 + lrow)*32 + slot*4);
      }
      #pragma unroll
      for (int mi = 0; mi < 4; mi++)
        #pragma unroll
        for (int ni = 0; ni < 4; ni++){
          acc[mi][ni] = __builtin_amdgcn_mfma_f32_16x16x32_bf16(ah[mi], bh[ni], acc[mi][ni], 0, 0, 0);
          acc[mi][ni] = __builtin_amdgcn_mfma_f32_16x16x32_bf16(ah[mi], bl[ni], acc[mi][ni], 0, 0, 0);
          acc[mi][ni] = __builtin_amdgcn_mfma_f32_16x16x32_bf16(al[mi], bh[ni], acc[mi][ni], 0, 0, 0);
        }
    }
  }

  float* P = D1p + (size_t)blockIdx.y * B_ * K_ + (size_t)b0 * K_;
  int rh = (l >> 4) << 2, cl = l & 15;
  #pragma unroll
  for (int mi = 0; mi < 4; mi++)
    #pragma unroll
    for (int ni = 0; ni < 4; ni++)
      #pragma unroll
      for (int r = 0; r < 4; r++){
        int row = wr + mi*16 + rh + r;
        int col = wc + ni*16 + cl;
        P[(size_t)row*K_ + col] = acc[mi][ni][r];
      }
}

// ---- tables partials over g (+ fused W2 bf16 store, JP-padded): n = k*129+j
__global__ __launch_bounds__(128) void tables_part_kernel(
    const float* __restrict__ wimg2, const float* __restrict__ wimg,
    float* __restrict__ sqp, float* __restrict__ crp,
    unsigned short* __restrict__ W2){
  int n  = blockIdx.x * 128 + threadIdx.x;   // [0,16512)
  int gs = blockIdx.y;
  int k = n / J_;
  int w2i = n + 3*k;                          // k*132 + j
  float s0=0,s1=0,s2=0,s3=0, c0=0,c1=0,c2=0,c3=0;
  int gbase = gs * (G_/GS_);
  #pragma unroll 2
  for (int g = gbase; g < gbase + G_/GS_; g += 4){
    float w0 = wimg2[(size_t)(g  )*KK_ + n];
    float w1 = wimg2[(size_t)(g+1)*KK_ + n];
    float w2 = wimg2[(size_t)(g+2)*KK_ + n];
    float w3 = wimg2[(size_t)(g+3)*KK_ + n];
    W2[(size_t)(g  )*KKP_ + w2i] = f2bf(w0);
    W2[(size_t)(g+1)*KKP_ + w2i] = f2bf(w1);
    W2[(size_t)(g+2)*KKP_ + w2i] = f2bf(w2);
    W2[(size_t)(g+3)*KKP_ + w2i] = f2bf(w3);
    s0 += w0*w0; s1 += w1*w1; s2 += w2*w2; s3 += w3*w3;
    c0 += wimg[(g  )*K_ + k]*w0;
    c1 += wimg[(g+1)*K_ + k]*w1;
    c2 += wimg[(g+2)*K_ + k]*w2;
    c3 += wimg[(g+3)*K_ + k]*w3;
  }
  sqp[(size_t)gs*KK_ + n] = (s0+s1)+(s2+s3);
  crp[(size_t)gs*KK_ + n] = (c0+c1)+(c2+c3);
}
__global__ __launch_bounds__(128) void tables_reduce_kernel(
    const float* __restrict__ sqp, const float* __restrict__ crp,
    float* __restrict__ sq2, float* __restrict__ cross){
  int n = blockIdx.x * 128 + threadIdx.x;
  float s = 0.f, c = 0.f;
  #pragma unroll
  for (int gs = 0; gs < GS_; gs++){
    s += sqp[(size_t)gs*KK_ + n];
    c += crp[(size_t)gs*KK_ + n];
  }
  sq2[n] = s; cross[n] = c;
}

// ---- encode+decode, TWO b's per block (512 thr); writes 2 R rows (bf16)
__global__ __launch_bounds__(512, 4) void encdec_kernel(
    const float* __restrict__ img,
    const float* __restrict__ wrec, const float* __restrict__ wrec2,
    const float* __restrict__ wrecT, const float* __restrict__ wrec2T,
    const unsigned short* __restrict__ W2,
    const float* __restrict__ c1norm, const float* __restrict__ w3norm,
    const float* __restrict__ w6norm, const float* __restrict__ sq2,
    const float* __restrict__ cross, const float* __restrict__ D1p,
    const float* __restrict__ inorm, unsigned short* __restrict__ Rm){
  __shared__ __align__(16) float simg[2][G_];
  __shared__ float sp[2][K_];
  __shared__ float sqv[2][JP_];
  __shared__ float slat[2][E2_];
  __shared__ float sd1[2][K_];
  __shared__ __align__(16) float sh16a[16][128];
  __shared__ __align__(16) float sh16b[16][128];
  __shared__ float sh4a[4][K_], sh4b[4][K_];
  __shared__ float xtra[4];
  __shared__ float redm[16], reds[16];
  __shared__ int   redi[16];

  int t = threadIdx.x;
  int b0 = blockIdx.x * 2, b1 = b0 + 1;
  int tt = t & 127, q = t >> 7;            // quarter split
  int ll = t & 31, gq = t >> 5;            // 16 g-groups of 32 (quad-packed)
  int wvid = t >> 6, lane = t & 63;

  // -- stage 1: D1 precomputed; softmax only
  simg[0][t] = img[b0*G_ + t];
  simg[1][t] = img[b1*G_ + t];
  float in0 = inorm[b0], in1 = inorm[b1];
  __syncthreads();
  float xh10 = -3e38f, xh11 = -3e38f;
  if (t < 128){
    const float* Dp = D1p;
    float d0 = Dp[b0*K_ + t] + Dp[(size_t)B_*K_ + b0*K_ + t]
             + Dp[(size_t)2*B_*K_ + b0*K_ + t] + Dp[(size_t)3*B_*K_ + b0*K_ + t];
    float d1 = Dp[b1*K_ + t] + Dp[(size_t)B_*K_ + b1*K_ + t]
             + Dp[(size_t)2*B_*K_ + b1*K_ + t] + Dp[(size_t)3*B_*K_ + b1*K_ + t];
    sd1[0][t] = d0; sd1[1][t] = d1;
    xh10 = -(in0 - 2.f*d0 + c1norm[t]) * (1.f/512.f);
    xh11 = -(in1 - 2.f*d1 + c1norm[t]) * (1.f/512.f);
  }
  float m10, s10, m11, s11;
  blockSoftmaxMS2(xh10, xh11, t < 128, redm, reds, t, m10, s10, m11, s11);
  if (t < 128){
    sp[0][t] = __expf(xh10 - m10) / s10;
    sp[1][t] = __expf(xh11 - m11) / s11;
  }
  __syncthreads();

  // -- stage 2: lat[e=tt] = sum_k xp1[k]*wrec[k][e] (shared weights)
  {
    float l00=0,l01=0, l10=0,l11=0;
    int k0 = q * 32;
    for (int k = k0; k < k0 + 32; k += 2){
      float w0 = wrec[(k  )*E2_ + tt];
      float w1 = wrec[(k+1)*E2_ + tt];
      l00 += sp[0][k]*w0; l01 += sp[0][k+1]*w1;
      l10 += sp[1][k]*w0; l11 += sp[1][k+1]*w1;
    }
    sh4a[q][tt] = l00 + l01;
    sh4b[q][tt] = l10 + l11;
  }
  __syncthreads();
  float lat0 = (sh4a[0][tt] + sh4a[1][tt]) + (sh4a[2][tt] + sh4a[3][tt]);
  float lat1 = (sh4b[0][tt] + sh4b[1][tt]) + (sh4b[2][tt] + sh4b[3][tt]);
  if (q == 0){ slat[0][tt] = lat0; slat[1][tt] = lat1; }
  float ln0, ln1;
  blockSum2((q == 0) ? lat0*lat0 : 0.f, (q == 0) ? lat1*lat1 : 0.f, redm, t, ln0, ln1);

  // -- stage 3: d3[k=tt] = sum_e lat[e]*wrecT[e][k] (shared weights)
  {
    float l00=0,l01=0, l10=0,l11=0;
    int e0 = q * 32;
    const float* rT = wrecT + tt;
    for (int e = e0; e < e0 + 32; e += 2){
      float w0 = rT[(e  )*K_];
      float w1 = rT[(e+1)*K_];
      l00 += slat[0][e]*w0; l01 += slat[0][e+1]*w1;
      l10 += slat[1][e]*w0; l11 += slat[1][e+1]*w1;
    }
    sh4a[q][tt] = l00 + l01;
    sh4b[q][tt] = l10 + l11;
  }
  __syncthreads();
  float xh30 = -3e38f, xh31 = -3e38f;
  if (t < 128){
    float d30 = (sh4a[0][t] + sh4a[1][t]) + (sh4a[2][t] + sh4a[3][t]);
    float d31 = (sh4b[0][t] + sh4b[1][t]) + (sh4b[2][t] + sh4b[3][t]);
    xh30 = -(ln0 - 2.f*d30 + w3norm[t]) * (1.f/128.f);
    xh31 = -(ln1 - 2.f*d31 + w3norm[t]) * (1.f/128.f);
  }
  float m30, s30, m31, s31; int idx0, idx1;
  blockSoftmaxMSI2(xh30, xh31, tt, t < 128, redm, reds, redi, t,
                   m30, s30, idx0, m31, s31, idx1);
  if (t < 128){
    sp[0][t] = __expf(xh30 - m30) / s30;
    sp[1][t] = __expf(xh31 - m31) / s31;
  }
  float dsq0 = in0 - 2.f*sd1[0][idx0] + c1norm[idx0];
  float dsq1 = in1 - 2.f*sd1[1][idx1] + c1norm[idx1];

  // -- stage 5: di[j] = sum_g simg[g]*W2[g][idx*JP+j]; quad-packed, dual idx
  {
    const unsigned short* Wb0 = W2 + (size_t)idx0 * JP_ + 4*ll;
    const unsigned short* Wb1 = W2 + (size_t)idx1 * JP_ + 4*ll;
    float p00=0,p01=0,p02=0,p03=0, p10=0,p11=0,p12=0,p13=0;
    int g0 = gq * 32;
    #pragma unroll 4
    for (int g = g0; g < g0 + 32; g++){
      uint2 w0 = *(const uint2*)(Wb0 + (size_t)g*KKP_);
      uint2 w1 = *(const uint2*)(Wb1 + (size_t)g*KKP_);
      float sv0 = simg[0][g], sv1 = simg[1][g];
      p00 += sv0 * __uint_as_float(w0.x << 16);
      p01 += sv0 * __uint_as_float(w0.x & 0xffff0000u);
      p02 += sv0 * __uint_as_float(w0.y << 16);
      p03 += sv0 * __uint_as_float(w0.y & 0xffff0000u);
      p10 += sv1 * __uint_as_float(w1.x << 16);
      p11 += sv1 * __uint_as_float(w1.x & 0xffff0000u);
      p12 += sv1 * __uint_as_float(w1.y << 16);
      p13 += sv1 * __uint_as_float(w1.y & 0xffff0000u);
    }
    float4 st0 = {p00,p01,p02,p03};
    float4 st1 = {p10,p11,p12,p13};
    *(float4*)&sh16a[gq][4*ll] = st0;
    *(float4*)&sh16b[gq][4*ll] = st1;
  }
  if (wvid < 2){
    int ib = wvid ? idx1 : idx0;
    const float* si = simg[wvid];
    const unsigned short* Wb8 = W2 + (size_t)ib * JP_ + 128;
    float s = 0.f;
    #pragma unroll
    for (int m = 0; m < 8; m++){
      int g = lane + 64*m;
      s += si[g] * bf2f(Wb8[(size_t)g * KKP_]);
    }
    #pragma unroll
    for (int off = 32; off > 0; off >>= 1) s += __shfl_down(s, off);
    if (lane == 0) xtra[wvid] = s;
  }
  __syncthreads();
  float xh20 = -3e38f, xh21 = -3e38f;
  if (t < J_){
    float di0, di1;
    if (t < 128){
      di0 = 0.f; di1 = 0.f;
      #pragma unroll
      for (int i = 0; i < 16; i++){ di0 += sh16a[i][t]; di1 += sh16b[i][t]; }
    } else { di0 = xtra[0]; di1 = xtra[1]; }
    int nb0 = idx0*J_ + t, nb1 = idx1*J_ + t;
    xh20 = -(dsq0 - 2.f*(di0 - cross[nb0]) + sq2[nb0]) * (1.f/512.f);
    xh21 = -(dsq1 - 2.f*(di1 - cross[nb1]) + sq2[nb1]) * (1.f/512.f);
  }
  float m20, s20, m21, s21;
  blockSoftmaxMS2(xh20, xh21, t < J_, redm, reds, t, m20, s20, m21, s21);
  if (t < J_){
    sqv[0][t] = __expf(xh20 - m20) / s20;
    sqv[1][t] = __expf(xh21 - m21) / s21;
  }
  __syncthreads();

  // -- stage 6: lat2[e=tt] = sum_j xp2[j]*wrec2[j][e] (shared weights)
  {
    float lv0 = 0.f, lv1 = 0.f;
    int j0 = (q == 0) ? 0 : (q*32 + 1);
    int j1 = q*32 + 33;
    for (int j = j0; j < j1; j++){
      float w = wrec2[j*E2_ + tt];
      lv0 += sqv[0][j]*w; lv1 += sqv[1][j]*w;
    }
    sh4a[q][tt] = lv0;
    sh4b[q][tt] = lv1;
  }
  __syncthreads();
  float l20 = (sh4a[0][tt] + sh4a[1][tt]) + (sh4a[2][tt] + sh4a[3][tt]);
  float l21 = (sh4b[0][tt] + sh4b[1][tt]) + (sh4b[2][tt] + sh4b[3][tt]);
  if (q == 0){ slat[0][tt] = l20; slat[1][tt] = l21; }
  float n20, n21;
  blockSum2((q == 0) ? l20*l20 : 0.f, (q == 0) ? l21*l21 : 0.f, redm, t, n20, n21);

  // -- stage 7: d6[j=tt] = sum_e lat2[e]*wrec2T[e][j] (shared weights)
  {
    float l00=0,l01=0, l10=0,l11=0;
    int e0 = q * 32;
    const float* rT = wrec2T + tt;
    for (int e = e0; e < e0 + 32; e += 2){
      float w0 = rT[(e  )*J_];
      float w1 = rT[(e+1)*J_];
      l00 += slat[0][e]*w0; l01 += slat[0][e+1]*w1;
      l10 += slat[1][e]*w0; l11 += slat[1][e+1]*w1;
    }
    sh4a[q][tt] = l00 + l01;
    sh4b[q][tt] = l10 + l11;
  }
  if (wvid < 2){
    const float* sl = slat[wvid];
    float s = sl[lane]*wrec2T[lane*J_ + 128] + sl[lane+64]*wrec2T[(lane+64)*J_ + 128];
    #pragma unroll
    for (int off = 32; off > 0; off >>= 1) s += __shfl_down(s, off);
    if (lane == 0) xtra[2 + wvid] = s;
  }
  __syncthreads();
  float xh60 = -3e38f, xh61 = -3e38f;
  if (t < J_){
    float d60, d61;
    if (t < 128){
      d60 = (sh4a[0][t] + sh4a[1][t]) + (sh4a[2][t] + sh4a[3][t]);
      d61 = (sh4b[0][t] + sh4b[1][t]) + (sh4b[2][t] + sh4b[3][t]);
    } else { d60 = xtra[2]; d61 = xtra[3]; }
    xh60 = -(n20 - 2.f*d60 + w6norm[t]) * (1.f/128.f);
    xh61 = -(n21 - 2.f*d61 + w6norm[t]) * (1.f/128.f);
  }
  float m60, s60, m61, s61;
  blockSoftmaxMS2(xh60, xh61, t < J_, redm, reds, t, m60, s60, m61, s61);
  if (t < J_){
    sqv[0][t] = __expf(xh60 - m60) / s60;
    sqv[1][t] = __expf(xh61 - m61) / s61;
  }
  __syncthreads();

  // -- R fill, packed uint (2 bf16 per store), both rows
  unsigned int* R0 = (unsigned int*)(Rm + (size_t)b0 * KKP_);
  unsigned int* R1 = (unsigned int*)(Rm + (size_t)b1 * KKP_);
  int k = t / 66;                          // JP/2 = 66
  int j2 = t - k*66;
  for (int kk2 = t; kk2 < KKP_/2; kk2 += 512){
    float v00 = 0.f, v01 = 0.f, v10 = 0.f, v11 = 0.f;
    if (kk2 < KK2_/2){
      int j = 2*j2;
      float pk0 = sp[0][k], pk1 = sp[1][k];
      bool jo0 = (j < J_), jo1 = (j+1 < J_);
      v00 = jo0 ? pk0 * sqv[0][j]   : 0.f;
      v01 = jo1 ? pk0 * sqv[0][j+1] : 0.f;
      v10 = jo0 ? pk1 * sqv[1][j]   : 0.f;
      v11 = jo1 ? pk1 * sqv[1][j+1] : 0.f;
    } else if (kk2 < KKE2_/2){
      int e = 2*(kk2 - KK2_/2);
      v00 = sp[0][e]; v01 = sp[0][e+1];
      v10 = sp[1][e]; v11 = sp[1][e+1];
    }
    R0[kk2] = (unsigned int)f2bf(v00) | ((unsigned int)f2bf(v01) << 16);
    R1[kk2] = (unsigned int)f2bf(v10) | ((unsigned int)f2bf(v11) << 16);
    j2 += 50;                              // 512 mod 66
    if (j2 >= 66){ j2 -= 66; k += 8; } else k += 7;
  }
}

// ---- big einsum as bf16 NT GEMM, split-K, BK=64, dbuf, XOR-swizzled LDS:
__global__ __launch_bounds__(256) void gemm_kernel(
    const unsigned short* __restrict__ Rm, const unsigned short* __restrict__ W2,
    unsigned short* __restrict__ part){
  __shared__ __align__(16) unsigned int lds[16384];
  auto lds3 = (__attribute__((address_space(3))) unsigned int*)lds;
  int tid = threadIdx.x;
  int l = tid & 63;
  int wv = tid >> 6;
  int wr = (wv >> 1) * 64, wc = (wv & 1) * 64;
  int b0 = blockIdx.y * 128, g0 = blockIdx.x * 128;
  size_t kkbase = (size_t)blockIdx.z * KCHUNK;

  int srow = tid >> 3;                     // [0,32)
  int cswz = (tid & 7) ^ (srow & 7);
  const unsigned short* ga = Rm + (size_t)(b0 + srow)*KKP_ + kkbase + cswz*8;
  const unsigned short* gb = W2 + (size_t)(g0 + srow)*KKP_ + kkbase + cswz*8;

  int lrow = l & 15, lh = l >> 4, p7 = l & 7;

  f32x4 zero4 = {0.f, 0.f, 0.f, 0.f};
  f32x4 acc[4][4];
  #pragma unroll
  for (int mi = 0; mi < 4; mi++)
    #pragma unroll
    for (int ni = 0; ni < 4; ni++) acc[mi][ni] = zero4;

  auto STAGE = [&](int bb){
    unsigned int base = bb * 8192;
    #pragma unroll
    for (int c = 0; c < 4; c++){
      GLOAD16(ga + (size_t)c*32*KKP_, lds3 + base + c*1024 + wv*256);
      GLOAD16(gb + (size_t)c*32*KKP_, lds3 + base + 4096 + c*1024 + wv*256);
    }
    ga += BK_; gb += BK_;
  };

  STAGE(0);
  int cur = 0;
  for (int s = 0; s < KSTEPS; s++){
    __syncthreads();
    if (s + 1 < KSTEPS) STAGE(cur ^ 1);
    const unsigned int* lA = lds + cur*8192;
    const unsigned int* lB = lA + 4096;
    #pragma unroll
    for (int s2 = 0; s2 < 2; s2++){
      int slot = ((s2 << 2) + lh) ^ p7;
      short8 af[4], bfv[4];
      #pragma unroll
      for (int mi = 0; mi < 4; mi++)
        af[mi] = *(const short8*)(lA + (wr + mi*16 + lrow)*32 + slot*4);
      #pragma unroll
      for (int ni = 0; ni < 4; ni++)
        bfv[ni] = *(const short8*)(lB + (wc + ni*16 + lrow)*32 + slot*4);
      #pragma unroll
      for (int mi = 0; mi < 4; mi++)
        #pragma unroll
        for (int ni = 0; ni < 4; ni++)
          acc[mi][ni] = __builtin_amdgcn_mfma_f32_16x16x32_bf16(af[mi], bfv[ni], acc[mi][ni], 0, 0, 0);
    }
    cur ^= 1;
  }

  unsigned short* P = part + ((size_t)blockIdx.z * B_ + b0) * G_ + g0;
  int rh = (l >> 4) << 2, cl = l & 15;
  #pragma unroll
  for (int mi = 0; mi < 4; mi++)
    #pragma unroll
    for (int ni = 0; ni < 4; ni++)
      #pragma unroll
      for (int r = 0; r < 4; r++){
        int row = wr + mi*16 + rh + r;
        int col = wc + ni*16 + cl;
        P[(size_t)row*G_ + col] = f2bf(acc[mi][ni][r]);
      }
}

// ---- loss[b] = mean_g ( (sum_z part_bf16[z][b][g]) - img[b][g] )^2
__global__ __launch_bounds__(128) void loss_kernel(
    const float* __restrict__ img, const unsigned short* __restrict__ part,
    float* __restrict__ out){
  __shared__ float redf[2];
  int t = threadIdx.x, b = blockIdx.x;
  float x0 = 0.f, x1 = 0.f, x2 = 0.f, x3 = 0.f;
  #pragma unroll
  for (int z = 0; z < SPLITS; z++){
    const unsigned short* pr = part + ((size_t)z*B_ + b)*G_ + 4*t;
    uint2 v = *(const uint2*)pr;
    x0 += __uint_as_float(v.x << 16);
    x1 += __uint_as_float(v.x & 0xffff0000u);
    x2 += __uint_as_float(v.y << 16);
    x3 += __uint_as_float(v.y & 0xffff0000u);
  }
  float4 iv = *(const float4*)(img + (size_t)b*G_ + 4*t);
  float d0 = x0 - iv.x, d1 = x1 - iv.y, d2 = x2 - iv.z, d3 = x3 - iv.w;
  float acc = (d0*d0 + d1*d1) + (d2*d2 + d3*d3);
  #pragma unroll
  for (int off = 32; off > 0; off >>= 1) acc += __shfl_down(acc, off);
  __syncthreads();
  if ((t & 63) == 0) redf[t >> 6] = acc;
  __syncthreads();
  if (t == 0) out[b] = (redf[0] + redf[1]) * (1.f/512.f);
}

extern "C" void kernel_launch(void* const* d_in, const int* in_sizes, int n_in,
                              void* d_out, int out_size, void* d_ws, size_t ws_size,
                              hipStream_t stream){
  (void)in_sizes; (void)n_in; (void)out_size; (void)ws_size;
  const float* img   = (const float*)d_in[0];
  const float* wimg  = (const float*)d_in[1];
  const float* wrec  = (const float*)d_in[2];
  const float* wrec2 = (const float*)d_in[3];
  const float* wimg2 = (const float*)d_in[4];
  float* out = (float*)d_out;

  char* ws = (char*)d_ws;
  size_t off = 0;
  auto alloc = [&](size_t bytes) -> void* {
    void* p = ws + off;
    off += (bytes + 255) & ~(size_t)255;
    return p;
  };
  unsigned short* W2   = (unsigned short*)alloc((size_t)G_ * KKP_ * 2);
  unsigned short* Rm   = (unsigned short*)alloc((size_t)B_ * KKP_ * 2);
  unsigned short* part = (unsigned short*)alloc((size_t)SPLITS * B_ * G_ * 2);
  float* sqp    = (float*)alloc((size_t)GS_ * KK_ * 4);
  float* crp    = (float*)alloc((size_t)GS_ * KK_ * 4);
  float* sq2    = (float*)alloc((size_t)KK_ * 4);
  float* cross  = (float*)alloc((size_t)KK_ * 4);
  float* c1norm = (float*)alloc(K_ * 4);
  float* w3norm = (float*)alloc(K_ * 4);
  float* w6norm = (float*)alloc(J_ * 4);
  float* wrecT  = (float*)alloc((size_t)K_ * E2_ * 4);
  float* wrec2T = (float*)alloc((size_t)J_ * E2_ * 4);
  unsigned short* ihi  = (unsigned short*)alloc((size_t)B_ * G_ * 2);
  unsigned short* ilo  = (unsigned short*)alloc((size_t)B_ * G_ * 2);
  unsigned short* wThi = (unsigned short*)alloc((size_t)K_ * G_ * 2);
  unsigned short* wTlo = (unsigned short*)alloc((size_t)K_ * G_ * 2);
  float* D1p   = (float*)alloc((size_t)4 * B_ * K_ * 4);
  float* inorm = (float*)alloc((size_t)B_ * 4);

  norms_kernel<<<dim3(70), dim3(1024), 0, stream>>>(wimg, wrec, wrec2,
      c1norm, w3norm, w6norm, wrecT, wrec2T, wThi, wTlo, W2);
  splitimg_kernel<<<dim3(B_), dim3(128), 0, stream>>>(img, ihi, ilo, inorm);
  d1gemm_kernel<<<dim3(8, 4), dim3(256), 0, stream>>>(ihi, ilo, wThi, wTlo, D1p);
  tables_part_kernel<<<dim3(129, GS_), dim3(128), 0, stream>>>(wimg2, wimg, sqp, crp, W2);
  tables_reduce_kernel<<<dim3(129), dim3(128), 0, stream>>>(sqp, crp, sq2, cross);
  encdec_kernel<<<dim3(512), dim3(512), 0, stream>>>(img, wrec, wrec2, wrecT, wrec2T, W2,
      c1norm, w3norm, w6norm, sq2, cross, D1p, inorm, Rm);
  gemm_kernel<<<dim3(4, 8, SPLITS), dim3(256), 0, stream>>>(Rm, W2, part);
  loss_kernel<<<dim3(1024), dim3(128), 0, stream>>>(img, part, out);
}

// Round 17
// 110.300 us; speedup vs baseline: 1.1865x; 1.1865x over previous
//
#include <hip/hip_runtime.h>

#define B_    1024
#define G_    512
#define K_    128
#define J_    129
#define JP_   132       /* padded j-stride inside W2/R blocks (8B-aligned pairs) */
#define E2_   128
#define KK_   16512     /* K_*J_  (tables sq2/cross layout) */
#define KK2_  16896     /* K_*JP_ (W2/R block region) */
#define KKE2_ 17024     /* KK2_ + K_ (appended wimg columns) */
#define KKP_  17408     /* padded: SPLITS*KCHUNK */
#define SPLITS 16
#define KCHUNK 1088     /* KKP_/SPLITS */
#define BK_   64
#define KSTEPS 17       /* KCHUNK/BK_ */
#define GS_   16        /* g-splits for table partials */

using short8 = __attribute__((ext_vector_type(8))) short;
using f32x4  = __attribute__((ext_vector_type(4))) float;

__device__ __forceinline__ float bf2f(unsigned short h){
  return __uint_as_float(((unsigned int)h) << 16);
}
__device__ __forceinline__ unsigned short f2bf(float f){
  unsigned int u = __float_as_uint(f);
  u += 0x7fffu + ((u >> 16) & 1u);          // round-to-nearest-even
  return (unsigned short)(u >> 16);
}

#define GLOAD16(gptr, ldst) __builtin_amdgcn_global_load_lds( \
    (const __attribute__((address_space(1))) unsigned int*)(gptr), \
    (__attribute__((address_space(3))) unsigned int*)(ldst), 16, 0, 0)

// ---- dual-b block reductions (512 thr, 8 waves); red buffers sized [16] ----
__device__ __forceinline__ void blockSum2(float v0, float v1, float* red, int t,
                                          float& r0, float& r1){
  #pragma unroll
  for (int off = 32; off > 0; off >>= 1){
    v0 += __shfl_down(v0, off);
    v1 += __shfl_down(v1, off);
  }
  __syncthreads();
  if ((t & 63) == 0){ red[t >> 6] = v0; red[8 + (t >> 6)] = v1; }
  __syncthreads();
  r0 = ((red[0] + red[1]) + (red[2] + red[3])) + ((red[4] + red[5]) + (red[6] + red[7]));
  r1 = ((red[8] + red[9]) + (red[10] + red[11])) + ((red[12] + red[13]) + (red[14] + red[15]));
  __syncthreads();
}

__device__ __forceinline__ void blockSoftmaxMS2(float x0, float x1, bool act,
    float* redm, float* reds, int t,
    float& m0o, float& s0o, float& m1o, float& s1o){
  float m0 = x0, s0 = act ? 1.f : 0.f;
  float m1 = x1, s1 = act ? 1.f : 0.f;
  #pragma unroll
  for (int off = 32; off > 0; off >>= 1){
    float om0 = __shfl_down(m0, off), os0 = __shfl_down(s0, off);
    float om1 = __shfl_down(m1, off), os1 = __shfl_down(s1, off);
    float nm0 = fmaxf(m0, om0);
    s0 = s0*__expf(m0 - nm0) + os0*__expf(om0 - nm0); m0 = nm0;
    float nm1 = fmaxf(m1, om1);
    s1 = s1*__expf(m1 - nm1) + os1*__expf(om1 - nm1); m1 = nm1;
  }
  __syncthreads();
  if ((t & 63) == 0){
    redm[t >> 6] = m0; reds[t >> 6] = s0;
    redm[8 + (t >> 6)] = m1; reds[8 + (t >> 6)] = s1;
  }
  __syncthreads();
  float gm0 = redm[0], gs0 = reds[0], gm1 = redm[8], gs1 = reds[8];
  #pragma unroll
  for (int w = 1; w < 8; w++){
    float om0 = redm[w], os0 = reds[w];
    float nm0 = fmaxf(gm0, om0);
    gs0 = gs0*__expf(gm0 - nm0) + os0*__expf(om0 - nm0); gm0 = nm0;
    float om1 = redm[8 + w], os1 = reds[8 + w];
    float nm1 = fmaxf(gm1, om1);
    gs1 = gs1*__expf(gm1 - nm1) + os1*__expf(om1 - nm1); gm1 = nm1;
  }
  m0o = gm0; s0o = gs0; m1o = gm1; s1o = gs1;
}

__device__ __forceinline__ void blockSoftmaxMSI2(float x0, float x1, int idx, bool act,
    float* redm, float* reds, int* redi, int t,
    float& m0o, float& s0o, int& i0o, float& m1o, float& s1o, int& i1o){
  float m0 = x0, s0 = act ? 1.f : 0.f; int i0 = idx;
  float m1 = x1, s1 = act ? 1.f : 0.f; int i1 = idx;
  #pragma unroll
  for (int off = 32; off > 0; off >>= 1){
    float om0 = __shfl_down(m0, off), os0 = __shfl_down(s0, off);
    int   oi0 = __shfl_down(i0, off);
    float om1 = __shfl_down(m1, off), os1 = __shfl_down(s1, off);
    int   oi1 = __shfl_down(i1, off);
    bool tk0 = (om0 > m0) || (om0 == m0 && oi0 < i0);
    float nm0 = fmaxf(m0, om0);
    s0 = s0*__expf(m0 - nm0) + os0*__expf(om0 - nm0);
    i0 = tk0 ? oi0 : i0; m0 = nm0;
    bool tk1 = (om1 > m1) || (om1 == m1 && oi1 < i1);
    float nm1 = fmaxf(m1, om1);
    s1 = s1*__expf(m1 - nm1) + os1*__expf(om1 - nm1);
    i1 = tk1 ? oi1 : i1; m1 = nm1;
  }
  __syncthreads();
  if ((t & 63) == 0){
    redm[t >> 6] = m0; reds[t >> 6] = s0; redi[t >> 6] = i0;
    redm[8 + (t >> 6)] = m1; reds[8 + (t >> 6)] = s1; redi[8 + (t >> 6)] = i1;
  }
  __syncthreads();
  float gm0 = redm[0], gs0 = reds[0]; int gi0 = redi[0];
  float gm1 = redm[8], gs1 = reds[8]; int gi1 = redi[8];
  #pragma unroll
  for (int w = 1; w < 8; w++){
    { float om = redm[w], os = reds[w]; int oi = redi[w];
      bool tk = (om > gm0) || (om == gm0 && oi < gi0);
      float nm = fmaxf(gm0, om);
      gs0 = gs0*__expf(gm0 - nm) + os*__expf(om - nm);
      gi0 = tk ? oi : gi0; gm0 = nm; }
    { float om = redm[8 + w], os = reds[8 + w]; int oi = redi[8 + w];
      bool tk = (om > gm1) || (om == gm1 && oi < gi1);
      float nm = fmaxf(gm1, om);
      gs1 = gs1*__expf(gm1 - nm) + os*__expf(om - nm);
      gi1 = tk ? oi : gi1; gm1 = nm; }
  }
  m0o = gm0; s0o = gs0; i0o = gi0; m1o = gm1; s1o = gs1; i1o = gi1;
}

// ---- norms + transposes (blocks 0-4) + W2 tail (blocks 5-68, 8 g's each)
__global__ __launch_bounds__(1024) void norms_kernel(
    const float* __restrict__ wimg, const float* __restrict__ wrec,
    const float* __restrict__ wrec2, float* __restrict__ c1norm,
    float* __restrict__ w3norm, float* __restrict__ w6norm,
    float* __restrict__ wrecT, float* __restrict__ wrec2T,
    unsigned short* __restrict__ W2){
  int t = threadIdx.x;
  if (blockIdx.x == 0){
    __shared__ float red[8][128];
    int k = t & 127, sl = t >> 7;
    float s = 0.f;
    int g0 = sl * (G_/8);
    for (int g = g0; g < g0 + G_/8; g++){
      float v = wimg[g*K_ + k]; s += v*v;
    }
    red[sl][k] = s;
    __syncthreads();
    if (t < 128){
      float r = 0.f;
      #pragma unroll
      for (int i = 0; i < 8; i++) r += red[i][t];
      c1norm[t] = r;
    }
  } else if (blockIdx.x == 1){
    int wave = t >> 6, lane = t & 63;
    for (int k = wave; k < K_; k += 16){
      float v0 = wrec[k*E2_ + lane], v1 = wrec[k*E2_ + 64 + lane];
      float s = v0*v0 + v1*v1;
      #pragma unroll
      for (int off = 32; off > 0; off >>= 1) s += __shfl_down(s, off);
      if (lane == 0) w3norm[k] = s;
    }
  } else if (blockIdx.x == 2){
    int wave = t >> 6, lane = t & 63;
    for (int j = wave; j < J_; j += 16){
      float v0 = wrec2[j*E2_ + lane], v1 = wrec2[j*E2_ + 64 + lane];
      float s = v0*v0 + v1*v1;
      #pragma unroll
      for (int off = 32; off > 0; off >>= 1) s += __shfl_down(s, off);
      if (lane == 0) w6norm[j] = s;
    }
  } else if (blockIdx.x == 3){
    for (int n = t; n < K_*E2_; n += 1024){
      int k = n >> 7, e = n & 127;
      wrecT[e*K_ + k] = wrec[n];
    }
  } else if (blockIdx.x == 4){
    for (int n = t; n < J_*E2_; n += 1024){
      int j = n >> 7, e = n & 127;
      wrec2T[e*J_ + j] = wrec2[n];
    }
  } else {
    // W2 tail for 8 g's: appended wimg cols, zero pads, zero j={129,130,131}
    int g = (blockIdx.x - 5) * 8 + (t >> 7);
    int col = t & 127;
    unsigned short* dst = W2 + (size_t)g * KKP_;
    dst[KK2_ + col]        = f2bf(wimg[g*K_ + col]);
    dst[KKE2_ + col]       = 0;
    dst[KKE2_ + 128 + col] = 0;
    dst[KKE2_ + 256 + col] = 0;
    dst[col*JP_ + 129] = 0;
    dst[col*JP_ + 130] = 0;
    dst[col*JP_ + 131] = 0;
  }
}

// ---- tables partials over g (+ fused W2 bf16 store, JP-padded): n = k*129+j
__global__ __launch_bounds__(128) void tables_part_kernel(
    const float* __restrict__ wimg2, const float* __restrict__ wimg,
    float* __restrict__ sqp, float* __restrict__ crp,
    unsigned short* __restrict__ W2){
  int n  = blockIdx.x * 128 + threadIdx.x;   // [0,16512)
  int gs = blockIdx.y;
  int k = n / J_;
  int w2i = n + 3*k;                          // k*132 + j
  float s0=0,s1=0,s2=0,s3=0, c0=0,c1=0,c2=0,c3=0;
  int gbase = gs * (G_/GS_);
  #pragma unroll 2
  for (int g = gbase; g < gbase + G_/GS_; g += 4){
    float w0 = wimg2[(size_t)(g  )*KK_ + n];
    float w1 = wimg2[(size_t)(g+1)*KK_ + n];
    float w2 = wimg2[(size_t)(g+2)*KK_ + n];
    float w3 = wimg2[(size_t)(g+3)*KK_ + n];
    W2[(size_t)(g  )*KKP_ + w2i] = f2bf(w0);
    W2[(size_t)(g+1)*KKP_ + w2i] = f2bf(w1);
    W2[(size_t)(g+2)*KKP_ + w2i] = f2bf(w2);
    W2[(size_t)(g+3)*KKP_ + w2i] = f2bf(w3);
    s0 += w0*w0; s1 += w1*w1; s2 += w2*w2; s3 += w3*w3;
    c0 += wimg[(g  )*K_ + k]*w0;
    c1 += wimg[(g+1)*K_ + k]*w1;
    c2 += wimg[(g+2)*K_ + k]*w2;
    c3 += wimg[(g+3)*K_ + k]*w3;
  }
  sqp[(size_t)gs*KK_ + n] = (s0+s1)+(s2+s3);
  crp[(size_t)gs*KK_ + n] = (c0+c1)+(c2+c3);
}
__global__ __launch_bounds__(128) void tables_reduce_kernel(
    const float* __restrict__ sqp, const float* __restrict__ crp,
    float* __restrict__ sq2, float* __restrict__ cross){
  int n = blockIdx.x * 128 + threadIdx.x;
  float s = 0.f, c = 0.f;
  #pragma unroll
  for (int gs = 0; gs < GS_; gs++){
    s += sqp[(size_t)gs*KK_ + n];
    c += crp[(size_t)gs*KK_ + n];
  }
  sq2[n] = s; cross[n] = c;
}

// ---- encode+decode, TWO b's per block (512 thr); writes 2 R rows (bf16)
__global__ __launch_bounds__(512, 4) void encdec_kernel(
    const float* __restrict__ img,  const float* __restrict__ wimg,
    const float* __restrict__ wrec, const float* __restrict__ wrec2,
    const float* __restrict__ wrecT, const float* __restrict__ wrec2T,
    const unsigned short* __restrict__ W2,
    const float* __restrict__ c1norm, const float* __restrict__ w3norm,
    const float* __restrict__ w6norm, const float* __restrict__ sq2,
    const float* __restrict__ cross, unsigned short* __restrict__ Rm){
  __shared__ __align__(16) float simg[2][G_];
  __shared__ float sp[2][K_];
  __shared__ float sqv[2][JP_];
  __shared__ float slat[2][E2_];
  __shared__ float sd1[2][K_];
  __shared__ __align__(16) float sh16a[16][128];
  __shared__ __align__(16) float sh16b[16][128];
  __shared__ float sh4a[4][K_], sh4b[4][K_];
  __shared__ float xtra[4];
  __shared__ float redm[16], reds[16];
  __shared__ int   redi[16];

  int t = threadIdx.x;
  int b0 = blockIdx.x * 2, b1 = b0 + 1;
  int tt = t & 127, q = t >> 7;            // quarter split
  int ll = t & 31, gq = t >> 5;            // 16 g-groups of 32 (quad-packed)
  int wvid = t >> 6, lane = t & 63;

  // -- stage 1: xp1 = softmax_k( -(||img-c_k||^2)/512 ), both b's
  simg[0][t] = img[b0*G_ + t];
  simg[1][t] = img[b1*G_ + t];
  __syncthreads();
  float a0 = simg[0][t], a1 = simg[1][t];
  float in0, in1;
  blockSum2(a0*a0, a1*a1, redm, t, in0, in1);

  {
    float p00=0,p01=0,p02=0,p03=0, p10=0,p11=0,p12=0,p13=0;
    int g0 = gq * 32;
    #pragma unroll 8
    for (int g = g0; g < g0 + 32; g++){
      float4 wv = *(const float4*)(wimg + g*K_ + 4*ll);   // shared weights
      float sv0 = simg[0][g], sv1 = simg[1][g];
      p00 += sv0*wv.x; p01 += sv0*wv.y; p02 += sv0*wv.z; p03 += sv0*wv.w;
      p10 += sv1*wv.x; p11 += sv1*wv.y; p12 += sv1*wv.z; p13 += sv1*wv.w;
    }
    float4 st0 = {p00,p01,p02,p03};
    float4 st1 = {p10,p11,p12,p13};
    *(float4*)&sh16a[gq][4*ll] = st0;
    *(float4*)&sh16b[gq][4*ll] = st1;
  }
  __syncthreads();
  float xh10 = -3e38f, xh11 = -3e38f;
  if (t < 128){
    float d0 = 0.f, d1 = 0.f;
    #pragma unroll
    for (int i = 0; i < 16; i++){ d0 += sh16a[i][t]; d1 += sh16b[i][t]; }
    sd1[0][t] = d0; sd1[1][t] = d1;
    xh10 = -(in0 - 2.f*d0 + c1norm[t]) * (1.f/512.f);
    xh11 = -(in1 - 2.f*d1 + c1norm[t]) * (1.f/512.f);
  }
  float m10, s10, m11, s11;
  blockSoftmaxMS2(xh10, xh11, t < 128, redm, reds, t, m10, s10, m11, s11);
  if (t < 128){
    sp[0][t] = __expf(xh10 - m10) / s10;
    sp[1][t] = __expf(xh11 - m11) / s11;
  }
  __syncthreads();

  // -- stage 2: lat[e=tt] = sum_k xp1[k]*wrec[k][e] (shared weights)
  {
    float l00=0,l01=0, l10=0,l11=0;
    int k0 = q * 32;
    for (int k = k0; k < k0 + 32; k += 2){
      float w0 = wrec[(k  )*E2_ + tt];
      float w1 = wrec[(k+1)*E2_ + tt];
      l00 += sp[0][k]*w0; l01 += sp[0][k+1]*w1;
      l10 += sp[1][k]*w0; l11 += sp[1][k+1]*w1;
    }
    sh4a[q][tt] = l00 + l01;
    sh4b[q][tt] = l10 + l11;
  }
  __syncthreads();
  float lat0 = (sh4a[0][tt] + sh4a[1][tt]) + (sh4a[2][tt] + sh4a[3][tt]);
  float lat1 = (sh4b[0][tt] + sh4b[1][tt]) + (sh4b[2][tt] + sh4b[3][tt]);
  if (q == 0){ slat[0][tt] = lat0; slat[1][tt] = lat1; }
  float ln0, ln1;
  blockSum2((q == 0) ? lat0*lat0 : 0.f, (q == 0) ? lat1*lat1 : 0.f, redm, t, ln0, ln1);

  // -- stage 3: d3[k=tt] = sum_e lat[e]*wrecT[e][k] (shared weights)
  {
    float l00=0,l01=0, l10=0,l11=0;
    int e0 = q * 32;
    const float* rT = wrecT + tt;
    for (int e = e0; e < e0 + 32; e += 2){
      float w0 = rT[(e  )*K_];
      float w1 = rT[(e+1)*K_];
      l00 += slat[0][e]*w0; l01 += slat[0][e+1]*w1;
      l10 += slat[1][e]*w0; l11 += slat[1][e+1]*w1;
    }
    sh4a[q][tt] = l00 + l01;
    sh4b[q][tt] = l10 + l11;
  }
  __syncthreads();
  float xh30 = -3e38f, xh31 = -3e38f;
  if (t < 128){
    float d30 = (sh4a[0][t] + sh4a[1][t]) + (sh4a[2][t] + sh4a[3][t]);
    float d31 = (sh4b[0][t] + sh4b[1][t]) + (sh4b[2][t] + sh4b[3][t]);
    xh30 = -(ln0 - 2.f*d30 + w3norm[t]) * (1.f/128.f);
    xh31 = -(ln1 - 2.f*d31 + w3norm[t]) * (1.f/128.f);
  }
  float m30, s30, m31, s31; int idx0, idx1;
  blockSoftmaxMSI2(xh30, xh31, tt, t < 128, redm, reds, redi, t,
                   m30, s30, idx0, m31, s31, idx1);
  if (t < 128){
    sp[0][t] = __expf(xh30 - m30) / s30;
    sp[1][t] = __expf(xh31 - m31) / s31;
  }
  float dsq0 = in0 - 2.f*sd1[0][idx0] + c1norm[idx0];
  float dsq1 = in1 - 2.f*sd1[1][idx1] + c1norm[idx1];

  // -- stage 5: di[j] = sum_g simg[g]*W2[g][idx*JP+j]; quad-packed, dual idx
  {
    const unsigned short* Wb0 = W2 + (size_t)idx0 * JP_ + 4*ll;
    const unsigned short* Wb1 = W2 + (size_t)idx1 * JP_ + 4*ll;
    float p00=0,p01=0,p02=0,p03=0, p10=0,p11=0,p12=0,p13=0;
    int g0 = gq * 32;
    #pragma unroll 4
    for (int g = g0; g < g0 + 32; g++){
      uint2 w0 = *(const uint2*)(Wb0 + (size_t)g*KKP_);
      uint2 w1 = *(const uint2*)(Wb1 + (size_t)g*KKP_);
      float sv0 = simg[0][g], sv1 = simg[1][g];
      p00 += sv0 * __uint_as_float(w0.x << 16);
      p01 += sv0 * __uint_as_float(w0.x & 0xffff0000u);
      p02 += sv0 * __uint_as_float(w0.y << 16);
      p03 += sv0 * __uint_as_float(w0.y & 0xffff0000u);
      p10 += sv1 * __uint_as_float(w1.x << 16);
      p11 += sv1 * __uint_as_float(w1.x & 0xffff0000u);
      p12 += sv1 * __uint_as_float(w1.y << 16);
      p13 += sv1 * __uint_as_float(w1.y & 0xffff0000u);
    }
    float4 st0 = {p00,p01,p02,p03};
    float4 st1 = {p10,p11,p12,p13};
    *(float4*)&sh16a[gq][4*ll] = st0;
    *(float4*)&sh16b[gq][4*ll] = st1;
  }
  if (wvid < 2){
    int ib = wvid ? idx1 : idx0;
    const float* si = simg[wvid];
    const unsigned short* Wb8 = W2 + (size_t)ib * JP_ + 128;
    float s = 0.f;
    #pragma unroll
    for (int m = 0; m < 8; m++){
      int g = lane + 64*m;
      s += si[g] * bf2f(Wb8[(size_t)g * KKP_]);
    }
    #pragma unroll
    for (int off = 32; off > 0; off >>= 1) s += __shfl_down(s, off);
    if (lane == 0) xtra[wvid] = s;
  }
  __syncthreads();
  float xh20 = -3e38f, xh21 = -3e38f;
  if (t < J_){
    float di0, di1;
    if (t < 128){
      di0 = 0.f; di1 = 0.f;
      #pragma unroll
      for (int i = 0; i < 16; i++){ di0 += sh16a[i][t]; di1 += sh16b[i][t]; }
    } else { di0 = xtra[0]; di1 = xtra[1]; }
    int nb0 = idx0*J_ + t, nb1 = idx1*J_ + t;
    xh20 = -(dsq0 - 2.f*(di0 - cross[nb0]) + sq2[nb0]) * (1.f/512.f);
    xh21 = -(dsq1 - 2.f*(di1 - cross[nb1]) + sq2[nb1]) * (1.f/512.f);
  }
  float m20, s20, m21, s21;
  blockSoftmaxMS2(xh20, xh21, t < J_, redm, reds, t, m20, s20, m21, s21);
  if (t < J_){
    sqv[0][t] = __expf(xh20 - m20) / s20;
    sqv[1][t] = __expf(xh21 - m21) / s21;
  }
  __syncthreads();

  // -- stage 6: lat2[e=tt] = sum_j xp2[j]*wrec2[j][e] (shared weights)
  {
    float lv0 = 0.f, lv1 = 0.f;
    int j0 = (q == 0) ? 0 : (q*32 + 1);
    int j1 = q*32 + 33;
    for (int j = j0; j < j1; j++){
      float w = wrec2[j*E2_ + tt];
      lv0 += sqv[0][j]*w; lv1 += sqv[1][j]*w;
    }
    sh4a[q][tt] = lv0;
    sh4b[q][tt] = lv1;
  }
  __syncthreads();
  float l20 = (sh4a[0][tt] + sh4a[1][tt]) + (sh4a[2][tt] + sh4a[3][tt]);
  float l21 = (sh4b[0][tt] + sh4b[1][tt]) + (sh4b[2][tt] + sh4b[3][tt]);
  if (q == 0){ slat[0][tt] = l20; slat[1][tt] = l21; }
  float n20, n21;
  blockSum2((q == 0) ? l20*l20 : 0.f, (q == 0) ? l21*l21 : 0.f, redm, t, n20, n21);

  // -- stage 7: d6[j=tt] = sum_e lat2[e]*wrec2T[e][j] (shared weights)
  {
    float l00=0,l01=0, l10=0,l11=0;
    int e0 = q * 32;
    const float* rT = wrec2T + tt;
    for (int e = e0; e < e0 + 32; e += 2){
      float w0 = rT[(e  )*J_];
      float w1 = rT[(e+1)*J_];
      l00 += slat[0][e]*w0; l01 += slat[0][e+1]*w1;
      l10 += slat[1][e]*w0; l11 += slat[1][e+1]*w1;
    }
    sh4a[q][tt] = l00 + l01;
    sh4b[q][tt] = l10 + l11;
  }
  if (wvid < 2){
    const float* sl = slat[wvid];
    float s = sl[lane]*wrec2T[lane*J_ + 128] + sl[lane+64]*wrec2T[(lane+64)*J_ + 128];
    #pragma unroll
    for (int off = 32; off > 0; off >>= 1) s += __shfl_down(s, off);
    if (lane == 0) xtra[2 + wvid] = s;
  }
  __syncthreads();
  float xh60 = -3e38f, xh61 = -3e38f;
  if (t < J_){
    float d60, d61;
    if (t < 128){
      d60 = (sh4a[0][t] + sh4a[1][t]) + (sh4a[2][t] + sh4a[3][t]);
      d61 = (sh4b[0][t] + sh4b[1][t]) + (sh4b[2][t] + sh4b[3][t]);
    } else { d60 = xtra[2]; d61 = xtra[3]; }
    xh60 = -(n20 - 2.f*d60 + w6norm[t]) * (1.f/128.f);
    xh61 = -(n21 - 2.f*d61 + w6norm[t]) * (1.f/128.f);
  }
  float m60, s60, m61, s61;
  blockSoftmaxMS2(xh60, xh61, t < J_, redm, reds, t, m60, s60, m61, s61);
  if (t < J_){
    sqv[0][t] = __expf(xh60 - m60) / s60;
    sqv[1][t] = __expf(xh61 - m61) / s61;
  }
  __syncthreads();

  // -- R fill, packed uint (2 bf16 per store), both rows
  unsigned int* R0 = (unsigned int*)(Rm + (size_t)b0 * KKP_);
  unsigned int* R1 = (unsigned int*)(Rm + (size_t)b1 * KKP_);
  int k = t / 66;                          // JP/2 = 66
  int j2 = t - k*66;
  for (int kk2 = t; kk2 < KKP_/2; kk2 += 512){
    float v00 = 0.f, v01 = 0.f, v10 = 0.f, v11 = 0.f;
    if (kk2 < KK2_/2){
      int j = 2*j2;
      float pk0 = sp[0][k], pk1 = sp[1][k];
      bool jo0 = (j < J_), jo1 = (j+1 < J_);
      v00 = jo0 ? pk0 * sqv[0][j]   : 0.f;
      v01 = jo1 ? pk0 * sqv[0][j+1] : 0.f;
      v10 = jo0 ? pk1 * sqv[1][j]   : 0.f;
      v11 = jo1 ? pk1 * sqv[1][j+1] : 0.f;
    } else if (kk2 < KKE2_/2){
      int e = 2*(kk2 - KK2_/2);
      v00 = sp[0][e]; v01 = sp[0][e+1];
      v10 = sp[1][e]; v11 = sp[1][e+1];
    }
    R0[kk2] = (unsigned int)f2bf(v00) | ((unsigned int)f2bf(v01) << 16);
    R1[kk2] = (unsigned int)f2bf(v10) | ((unsigned int)f2bf(v11) << 16);
    j2 += 50;                              // 512 mod 66
    if (j2 >= 66){ j2 -= 66; k += 8; } else k += 7;
  }
}

// ---- big einsum as bf16 NT GEMM, split-K, BK=64, dbuf, XOR-swizzled LDS:
// part[z][b][g] = sum_{kk in chunk z} R[b,kk]*W2[g,kk]   (part stored bf16)
__global__ __launch_bounds__(256) void gemm_kernel(
    const unsigned short* __restrict__ Rm, const unsigned short* __restrict__ W2,
    unsigned short* __restrict__ part){
  // per buffer: A[128][64]bf16 (16KB=4096u) + B same; 2 buffers = 64 KB
  __shared__ __align__(16) unsigned int lds[16384];
  auto lds3 = (__attribute__((address_space(3))) unsigned int*)lds;
  int tid = threadIdx.x;
  int l = tid & 63;
  int wv = tid >> 6;
  int wr = (wv >> 1) * 64, wc = (wv & 1) * 64;
  int b0 = blockIdx.y * 128, g0 = blockIdx.x * 128;
  size_t kkbase = (size_t)blockIdx.z * KCHUNK;

  // staging: thread covers row (tid>>3) [+32 per call], 16B chunk (tid&7),
  // with global chunk pre-swizzled so swizzled-read is conflict-free (rule #21)
  int srow = tid >> 3;                     // [0,32)
  int cswz = (tid & 7) ^ (srow & 7);       // row&7 invariant across +32-row calls
  const unsigned short* ga = Rm + (size_t)(b0 + srow)*KKP_ + kkbase + cswz*8;
  const unsigned short* gb = W2 + (size_t)(g0 + srow)*KKP_ + kkbase + cswz*8;

  int lrow = l & 15, lh = l >> 4, p7 = l & 7;

  f32x4 zero4 = {0.f, 0.f, 0.f, 0.f};
  f32x4 acc[4][4];
  #pragma unroll
  for (int mi = 0; mi < 4; mi++)
    #pragma unroll
    for (int ni = 0; ni < 4; ni++) acc[mi][ni] = zero4;

  auto STAGE = [&](int bb){
    unsigned int base = bb * 8192;
    #pragma unroll
    for (int c = 0; c < 4; c++){
      GLOAD16(ga + (size_t)c*32*KKP_, lds3 + base + c*1024 + wv*256);
      GLOAD16(gb + (size_t)c*32*KKP_, lds3 + base + 4096 + c*1024 + wv*256);
    }
    ga += BK_; gb += BK_;
  };

  STAGE(0);                                // prologue: tile 0 -> buffer 0
  int cur = 0;
  for (int s = 0; s < KSTEPS; s++){
    __syncthreads();                       // vmcnt drain: buf[cur] ready
    if (s + 1 < KSTEPS) STAGE(cur ^ 1);
    const unsigned int* lA = lds + cur*8192;
    const unsigned int* lB = lA + 4096;
    #pragma unroll
    for (int s2 = 0; s2 < 2; s2++){
      int slot = ((s2 << 2) + lh) ^ p7;    // un-swizzle on read
      short8 af[4], bfv[4];
      #pragma unroll
      for (int mi = 0; mi < 4; mi++)
        af[mi] = *(const short8*)(lA + (wr + mi*16 + lrow)*32 + slot*4);
      #pragma unroll
      for (int ni = 0; ni < 4; ni++)
        bfv[ni] = *(const short8*)(lB + (wc + ni*16 + lrow)*32 + slot*4);
      #pragma unroll
      for (int mi = 0; mi < 4; mi++)
        #pragma unroll
        for (int ni = 0; ni < 4; ni++)
          acc[mi][ni] = __builtin_amdgcn_mfma_f32_16x16x32_bf16(af[mi], bfv[ni], acc[mi][ni], 0, 0, 0);
    }
    cur ^= 1;
  }

  unsigned short* P = part + ((size_t)blockIdx.z * B_ + b0) * G_ + g0;
  int rh = (l >> 4) << 2, cl = l & 15;
  #pragma unroll
  for (int mi = 0; mi < 4; mi++)
    #pragma unroll
    for (int ni = 0; ni < 4; ni++)
      #pragma unroll
      for (int r = 0; r < 4; r++){
        int row = wr + mi*16 + rh + r;
        int col = wc + ni*16 + cl;
        P[(size_t)row*G_ + col] = f2bf(acc[mi][ni][r]);
      }
}

// ---- loss[b] = mean_g ( (sum_z part_bf16[z][b][g]) - img[b][g] )^2
__global__ __launch_bounds__(128) void loss_kernel(
    const float* __restrict__ img, const unsigned short* __restrict__ part,
    float* __restrict__ out){
  __shared__ float redf[2];
  int t = threadIdx.x, b = blockIdx.x;
  // each thread owns 4 consecutive g (t*4), summing 16 bf16 planes
  float x0 = 0.f, x1 = 0.f, x2 = 0.f, x3 = 0.f;
  #pragma unroll
  for (int z = 0; z < SPLITS; z++){
    const unsigned short* pr = part + ((size_t)z*B_ + b)*G_ + 4*t;
    uint2 v = *(const uint2*)pr;
    x0 += __uint_as_float(v.x << 16);
    x1 += __uint_as_float(v.x & 0xffff0000u);
    x2 += __uint_as_float(v.y << 16);
    x3 += __uint_as_float(v.y & 0xffff0000u);
  }
  float4 iv = *(const float4*)(img + (size_t)b*G_ + 4*t);
  float d0 = x0 - iv.x, d1 = x1 - iv.y, d2 = x2 - iv.z, d3 = x3 - iv.w;
  float acc = (d0*d0 + d1*d1) + (d2*d2 + d3*d3);
  #pragma unroll
  for (int off = 32; off > 0; off >>= 1) acc += __shfl_down(acc, off);
  __syncthreads();
  if ((t & 63) == 0) redf[t >> 6] = acc;
  __syncthreads();
  if (t == 0) out[b] = (redf[0] + redf[1]) * (1.f/512.f);
}

extern "C" void kernel_launch(void* const* d_in, const int* in_sizes, int n_in,
                              void* d_out, int out_size, void* d_ws, size_t ws_size,
                              hipStream_t stream){
  (void)in_sizes; (void)n_in; (void)out_size; (void)ws_size;
  const float* img   = (const float*)d_in[0];
  const float* wimg  = (const float*)d_in[1];
  const float* wrec  = (const float*)d_in[2];
  const float* wrec2 = (const float*)d_in[3];
  const float* wimg2 = (const float*)d_in[4];
  float* out = (float*)d_out;

  char* ws = (char*)d_ws;
  size_t off = 0;
  auto alloc = [&](size_t bytes) -> void* {
    void* p = ws + off;
    off += (bytes + 255) & ~(size_t)255;
    return p;
  };
  unsigned short* W2   = (unsigned short*)alloc((size_t)G_ * KKP_ * 2);
  unsigned short* Rm   = (unsigned short*)alloc((size_t)B_ * KKP_ * 2);
  unsigned short* part = (unsigned short*)alloc((size_t)SPLITS * B_ * G_ * 2);
  float* sqp    = (float*)alloc((size_t)GS_ * KK_ * 4);
  float* crp    = (float*)alloc((size_t)GS_ * KK_ * 4);
  float* sq2    = (float*)alloc((size_t)KK_ * 4);
  float* cross  = (float*)alloc((size_t)KK_ * 4);
  float* c1norm = (float*)alloc(K_ * 4);
  float* w3norm = (float*)alloc(K_ * 4);
  float* w6norm = (float*)alloc(J_ * 4);
  float* wrecT  = (float*)alloc((size_t)K_ * E2_ * 4);
  float* wrec2T = (float*)alloc((size_t)J_ * E2_ * 4);

  norms_kernel<<<dim3(69), dim3(1024), 0, stream>>>(wimg, wrec, wrec2, c1norm, w3norm, w6norm, wrecT, wrec2T, W2);
  tables_part_kernel<<<dim3(129, GS_), dim3(128), 0, stream>>>(wimg2, wimg, sqp, crp, W2);
  tables_reduce_kernel<<<dim3(129), dim3(128), 0, stream>>>(sqp, crp, sq2, cross);
  encdec_kernel<<<dim3(512), dim3(512), 0, stream>>>(img, wimg, wrec, wrec2, wrecT, wrec2T, W2,
      c1norm, w3norm, w6norm, sq2, cross, Rm);
  gemm_kernel<<<dim3(4, 8, SPLITS), dim3(256), 0, stream>>>(Rm, W2, part);
  loss_kernel<<<dim3(1024), dim3(128), 0, stream>>>(img, part, out);
}

// Round 18
// 108.173 us; speedup vs baseline: 1.2098x; 1.0197x over previous
//
#include <hip/hip_runtime.h>

#define B_    1024
#define G_    512
#define K_    128
#define J_    129
#define JP_   132       /* padded j-stride inside W2/R blocks (8B-aligned pairs) */
#define E2_   128
#define KK_   16512     /* K_*J_  (tables sq2/cross layout) */
#define KK2_  16896     /* K_*JP_ (W2/R block region) */
#define KKE2_ 17024     /* KK2_ + K_ (appended wimg columns) */
#define KKP_  17408     /* padded: SPLITS*KCHUNK */
#define SPLITS 16
#define KCHUNK 1088     /* KKP_/SPLITS */
#define BK_   64
#define KSTEPS 17       /* KCHUNK/BK_ */
#define GS_   16        /* g-splits for table partials */

using short8 = __attribute__((ext_vector_type(8))) short;
using f32x4  = __attribute__((ext_vector_type(4))) float;

__device__ __forceinline__ float bf2f(unsigned short h){
  return __uint_as_float(((unsigned int)h) << 16);
}
__device__ __forceinline__ unsigned short f2bf(float f){
  unsigned int u = __float_as_uint(f);
  u += 0x7fffu + ((u >> 16) & 1u);          // round-to-nearest-even
  return (unsigned short)(u >> 16);
}

#define GLOAD16(gptr, ldst) __builtin_amdgcn_global_load_lds( \
    (const __attribute__((address_space(1))) unsigned int*)(gptr), \
    (__attribute__((address_space(3))) unsigned int*)(ldst), 16, 0, 0)

// ---- dual-b block reductions, ONE barrier each (dedicated buffers per call)
// buf layout: [0..7]=m0/v0 per wave, [8..15]=m1/v1, [16..23]=s0, [24..31]=s1
__device__ __forceinline__ void blockSum2(float v0, float v1, float* buf, int t,
                                          float& r0, float& r1){
  #pragma unroll
  for (int off = 32; off > 0; off >>= 1){
    v0 += __shfl_down(v0, off);
    v1 += __shfl_down(v1, off);
  }
  if ((t & 63) == 0){ buf[t >> 6] = v0; buf[8 + (t >> 6)] = v1; }
  __syncthreads();
  r0 = ((buf[0] + buf[1]) + (buf[2] + buf[3])) + ((buf[4] + buf[5]) + (buf[6] + buf[7]));
  r1 = ((buf[8] + buf[9]) + (buf[10] + buf[11])) + ((buf[12] + buf[13]) + (buf[14] + buf[15]));
}

__device__ __forceinline__ void blockSoftmaxMS2(float x0, float x1, bool act,
    float* buf, int t,
    float& m0o, float& s0o, float& m1o, float& s1o){
  float m0 = x0, s0 = act ? 1.f : 0.f;
  float m1 = x1, s1 = act ? 1.f : 0.f;
  #pragma unroll
  for (int off = 32; off > 0; off >>= 1){
    float om0 = __shfl_down(m0, off), os0 = __shfl_down(s0, off);
    float om1 = __shfl_down(m1, off), os1 = __shfl_down(s1, off);
    float nm0 = fmaxf(m0, om0);
    s0 = s0*__expf(m0 - nm0) + os0*__expf(om0 - nm0); m0 = nm0;
    float nm1 = fmaxf(m1, om1);
    s1 = s1*__expf(m1 - nm1) + os1*__expf(om1 - nm1); m1 = nm1;
  }
  if ((t & 63) == 0){
    buf[t >> 6] = m0;       buf[16 + (t >> 6)] = s0;
    buf[8 + (t >> 6)] = m1; buf[24 + (t >> 6)] = s1;
  }
  __syncthreads();
  float gm0 = buf[0], gs0 = buf[16], gm1 = buf[8], gs1 = buf[24];
  #pragma unroll
  for (int w = 1; w < 8; w++){
    float om0 = buf[w], os0 = buf[16 + w];
    float nm0 = fmaxf(gm0, om0);
    gs0 = gs0*__expf(gm0 - nm0) + os0*__expf(om0 - nm0); gm0 = nm0;
    float om1 = buf[8 + w], os1 = buf[24 + w];
    float nm1 = fmaxf(gm1, om1);
    gs1 = gs1*__expf(gm1 - nm1) + os1*__expf(om1 - nm1); gm1 = nm1;
  }
  m0o = gm0; s0o = gs0; m1o = gm1; s1o = gs1;
}

__device__ __forceinline__ void blockSoftmaxMSI2(float x0, float x1, int idx, bool act,
    float* buf, int* ibuf, int t,
    float& m0o, float& s0o, int& i0o, float& m1o, float& s1o, int& i1o){
  float m0 = x0, s0 = act ? 1.f : 0.f; int i0 = idx;
  float m1 = x1, s1 = act ? 1.f : 0.f; int i1 = idx;
  #pragma unroll
  for (int off = 32; off > 0; off >>= 1){
    float om0 = __shfl_down(m0, off), os0 = __shfl_down(s0, off);
    int   oi0 = __shfl_down(i0, off);
    float om1 = __shfl_down(m1, off), os1 = __shfl_down(s1, off);
    int   oi1 = __shfl_down(i1, off);
    bool tk0 = (om0 > m0) || (om0 == m0 && oi0 < i0);
    float nm0 = fmaxf(m0, om0);
    s0 = s0*__expf(m0 - nm0) + os0*__expf(om0 - nm0);
    i0 = tk0 ? oi0 : i0; m0 = nm0;
    bool tk1 = (om1 > m1) || (om1 == m1 && oi1 < i1);
    float nm1 = fmaxf(m1, om1);
    s1 = s1*__expf(m1 - nm1) + os1*__expf(om1 - nm1);
    i1 = tk1 ? oi1 : i1; m1 = nm1;
  }
  if ((t & 63) == 0){
    buf[t >> 6] = m0;       buf[16 + (t >> 6)] = s0; ibuf[t >> 6] = i0;
    buf[8 + (t >> 6)] = m1; buf[24 + (t >> 6)] = s1; ibuf[8 + (t >> 6)] = i1;
  }
  __syncthreads();
  float gm0 = buf[0], gs0 = buf[16]; int gi0 = ibuf[0];
  float gm1 = buf[8], gs1 = buf[24]; int gi1 = ibuf[8];
  #pragma unroll
  for (int w = 1; w < 8; w++){
    { float om = buf[w], os = buf[16 + w]; int oi = ibuf[w];
      bool tk = (om > gm0) || (om == gm0 && oi < gi0);
      float nm = fmaxf(gm0, om);
      gs0 = gs0*__expf(gm0 - nm) + os*__expf(om - nm);
      gi0 = tk ? oi : gi0; gm0 = nm; }
    { float om = buf[8 + w], os = buf[24 + w]; int oi = ibuf[8 + w];
      bool tk = (om > gm1) || (om == gm1 && oi < gi1);
      float nm = fmaxf(gm1, om);
      gs1 = gs1*__expf(gm1 - nm) + os*__expf(om - nm);
      gi1 = tk ? oi : gi1; gm1 = nm; }
  }
  m0o = gm0; s0o = gs0; i0o = gi0; m1o = gm1; s1o = gs1; i1o = gi1;
}

// ---- norms + transposes (blocks 0-4) + W2 tail (blocks 5-68, 8 g's each)
__global__ __launch_bounds__(1024) void norms_kernel(
    const float* __restrict__ wimg, const float* __restrict__ wrec,
    const float* __restrict__ wrec2, float* __restrict__ c1norm,
    float* __restrict__ w3norm, float* __restrict__ w6norm,
    float* __restrict__ wrecT, float* __restrict__ wrec2T,
    unsigned short* __restrict__ W2){
  int t = threadIdx.x;
  if (blockIdx.x == 0){
    __shared__ float red[8][128];
    int k = t & 127, sl = t >> 7;
    float s = 0.f;
    int g0 = sl * (G_/8);
    for (int g = g0; g < g0 + G_/8; g++){
      float v = wimg[g*K_ + k]; s += v*v;
    }
    red[sl][k] = s;
    __syncthreads();
    if (t < 128){
      float r = 0.f;
      #pragma unroll
      for (int i = 0; i < 8; i++) r += red[i][t];
      c1norm[t] = r;
    }
  } else if (blockIdx.x == 1){
    int wave = t >> 6, lane = t & 63;
    for (int k = wave; k < K_; k += 16){
      float v0 = wrec[k*E2_ + lane], v1 = wrec[k*E2_ + 64 + lane];
      float s = v0*v0 + v1*v1;
      #pragma unroll
      for (int off = 32; off > 0; off >>= 1) s += __shfl_down(s, off);
      if (lane == 0) w3norm[k] = s;
    }
  } else if (blockIdx.x == 2){
    int wave = t >> 6, lane = t & 63;
    for (int j = wave; j < J_; j += 16){
      float v0 = wrec2[j*E2_ + lane], v1 = wrec2[j*E2_ + 64 + lane];
      float s = v0*v0 + v1*v1;
      #pragma unroll
      for (int off = 32; off > 0; off >>= 1) s += __shfl_down(s, off);
      if (lane == 0) w6norm[j] = s;
    }
  } else if (blockIdx.x == 3){
    for (int n = t; n < K_*E2_; n += 1024){
      int k = n >> 7, e = n & 127;
      wrecT[e*K_ + k] = wrec[n];
    }
  } else if (blockIdx.x == 4){
    for (int n = t; n < J_*E2_; n += 1024){
      int j = n >> 7, e = n & 127;
      wrec2T[e*J_ + j] = wrec2[n];
    }
  } else {
    // W2 tail for 8 g's: appended wimg cols, zero pads, zero j={129,130,131}
    int g = (blockIdx.x - 5) * 8 + (t >> 7);
    int col = t & 127;
    unsigned short* dst = W2 + (size_t)g * KKP_;
    dst[KK2_ + col]        = f2bf(wimg[g*K_ + col]);
    dst[KKE2_ + col]       = 0;
    dst[KKE2_ + 128 + col] = 0;
    dst[KKE2_ + 256 + col] = 0;
    dst[col*JP_ + 129] = 0;
    dst[col*JP_ + 130] = 0;
    dst[col*JP_ + 131] = 0;
  }
}

// ---- tables partials over g (+ fused W2 bf16 store, JP-padded): n = k*129+j
__global__ __launch_bounds__(128) void tables_part_kernel(
    const float* __restrict__ wimg2, const float* __restrict__ wimg,
    float* __restrict__ sqp, float* __restrict__ crp,
    unsigned short* __restrict__ W2){
  int n  = blockIdx.x * 128 + threadIdx.x;   // [0,16512)
  int gs = blockIdx.y;
  int k = n / J_;
  int w2i = n + 3*k;                          // k*132 + j
  float s0=0,s1=0,s2=0,s3=0, c0=0,c1=0,c2=0,c3=0;
  int gbase = gs * (G_/GS_);
  #pragma unroll 2
  for (int g = gbase; g < gbase + G_/GS_; g += 4){
    float w0 = wimg2[(size_t)(g  )*KK_ + n];
    float w1 = wimg2[(size_t)(g+1)*KK_ + n];
    float w2 = wimg2[(size_t)(g+2)*KK_ + n];
    float w3 = wimg2[(size_t)(g+3)*KK_ + n];
    W2[(size_t)(g  )*KKP_ + w2i] = f2bf(w0);
    W2[(size_t)(g+1)*KKP_ + w2i] = f2bf(w1);
    W2[(size_t)(g+2)*KKP_ + w2i] = f2bf(w2);
    W2[(size_t)(g+3)*KKP_ + w2i] = f2bf(w3);
    s0 += w0*w0; s1 += w1*w1; s2 += w2*w2; s3 += w3*w3;
    c0 += wimg[(g  )*K_ + k]*w0;
    c1 += wimg[(g+1)*K_ + k]*w1;
    c2 += wimg[(g+2)*K_ + k]*w2;
    c3 += wimg[(g+3)*K_ + k]*w3;
  }
  sqp[(size_t)gs*KK_ + n] = (s0+s1)+(s2+s3);
  crp[(size_t)gs*KK_ + n] = (c0+c1)+(c2+c3);
}
__global__ __launch_bounds__(128) void tables_reduce_kernel(
    const float* __restrict__ sqp, const float* __restrict__ crp,
    float* __restrict__ sq2, float* __restrict__ cross){
  int n = blockIdx.x * 128 + threadIdx.x;
  float s = 0.f, c = 0.f;
  #pragma unroll
  for (int gs = 0; gs < GS_; gs++){
    s += sqp[(size_t)gs*KK_ + n];
    c += crp[(size_t)gs*KK_ + n];
  }
  sq2[n] = s; cross[n] = c;
}

// ---- encode+decode, TWO b's per block (512 thr); writes 2 R rows (bf16)
__global__ __launch_bounds__(512, 4) void encdec_kernel(
    const float* __restrict__ img,  const float* __restrict__ wimg,
    const float* __restrict__ wrec, const float* __restrict__ wrec2,
    const float* __restrict__ wrecT, const float* __restrict__ wrec2T,
    const unsigned short* __restrict__ W2,
    const float* __restrict__ c1norm, const float* __restrict__ w3norm,
    const float* __restrict__ w6norm, const float* __restrict__ sq2,
    const float* __restrict__ cross, unsigned short* __restrict__ Rm){
  __shared__ __align__(16) float simg[2][G_];
  __shared__ float sp[2][K_];
  __shared__ float sqv[2][JP_];
  __shared__ float slat[2][E2_];
  __shared__ float sd1[2][K_];
  __shared__ __align__(16) float sh16a[16][128];
  __shared__ __align__(16) float sh16b[16][128];
  __shared__ float sh4a[4][K_], sh4b[4][K_];
  __shared__ float xtra[4];
  __shared__ float rr[7][32];              // dedicated reduction buffers
  __shared__ int   ri[16];

  int t = threadIdx.x;
  int b0 = blockIdx.x * 2, b1 = b0 + 1;
  int tt = t & 127, q = t >> 7;            // quarter split
  int ll = t & 31, gq = t >> 5;            // 16 g-groups of 32 (quad-packed)
  int wvid = t >> 6, lane = t & 63;

  // -- stage 1: xp1 = softmax_k( -(||img-c_k||^2)/512 ), both b's
  simg[0][t] = img[b0*G_ + t];
  simg[1][t] = img[b1*G_ + t];
  __syncthreads();
  float a0 = simg[0][t], a1 = simg[1][t];
  float in0, in1;
  blockSum2(a0*a0, a1*a1, rr[0], t, in0, in1);

  {
    float p00=0,p01=0,p02=0,p03=0, p10=0,p11=0,p12=0,p13=0;
    int g0 = gq * 32;
    #pragma unroll 8
    for (int g = g0; g < g0 + 32; g++){
      float4 wv = *(const float4*)(wimg + g*K_ + 4*ll);   // shared weights
      float sv0 = simg[0][g], sv1 = simg[1][g];
      p00 += sv0*wv.x; p01 += sv0*wv.y; p02 += sv0*wv.z; p03 += sv0*wv.w;
      p10 += sv1*wv.x; p11 += sv1*wv.y; p12 += sv1*wv.z; p13 += sv1*wv.w;
    }
    float4 st0 = {p00,p01,p02,p03};
    float4 st1 = {p10,p11,p12,p13};
    *(float4*)&sh16a[gq][4*ll] = st0;
    *(float4*)&sh16b[gq][4*ll] = st1;
  }
  __syncthreads();
  float xh10 = -3e38f, xh11 = -3e38f;
  if (t < 128){
    float d0 = 0.f, d1 = 0.f;
    #pragma unroll
    for (int i = 0; i < 16; i++){ d0 += sh16a[i][t]; d1 += sh16b[i][t]; }
    sd1[0][t] = d0; sd1[1][t] = d1;
    xh10 = -(in0 - 2.f*d0 + c1norm[t]) * (1.f/512.f);
    xh11 = -(in1 - 2.f*d1 + c1norm[t]) * (1.f/512.f);
  }
  float m10, s10, m11, s11;
  blockSoftmaxMS2(xh10, xh11, t < 128, rr[1], t, m10, s10, m11, s11);
  if (t < 128){
    sp[0][t] = __expf(xh10 - m10) / s10;
    sp[1][t] = __expf(xh11 - m11) / s11;
  }
  __syncthreads();

  // -- stage 2: lat[e=tt] = sum_k xp1[k]*wrec[k][e] (shared weights)
  {
    float l00=0,l01=0, l10=0,l11=0;
    int k0 = q * 32;
    for (int k = k0; k < k0 + 32; k += 2){
      float w0 = wrec[(k  )*E2_ + tt];
      float w1 = wrec[(k+1)*E2_ + tt];
      l00 += sp[0][k]*w0; l01 += sp[0][k+1]*w1;
      l10 += sp[1][k]*w0; l11 += sp[1][k+1]*w1;
    }
    sh4a[q][tt] = l00 + l01;
    sh4b[q][tt] = l10 + l11;
  }
  __syncthreads();
  float lat0 = (sh4a[0][tt] + sh4a[1][tt]) + (sh4a[2][tt] + sh4a[3][tt]);
  float lat1 = (sh4b[0][tt] + sh4b[1][tt]) + (sh4b[2][tt] + sh4b[3][tt]);
  if (q == 0){ slat[0][tt] = lat0; slat[1][tt] = lat1; }
  float ln0, ln1;
  blockSum2((q == 0) ? lat0*lat0 : 0.f, (q == 0) ? lat1*lat1 : 0.f, rr[2], t, ln0, ln1);

  // -- stage 3: d3[k=tt] = sum_e lat[e]*wrecT[e][k] (shared weights)
  {
    float l00=0,l01=0, l10=0,l11=0;
    int e0 = q * 32;
    const float* rT = wrecT + tt;
    for (int e = e0; e < e0 + 32; e += 2){
      float w0 = rT[(e  )*K_];
      float w1 = rT[(e+1)*K_];
      l00 += slat[0][e]*w0; l01 += slat[0][e+1]*w1;
      l10 += slat[1][e]*w0; l11 += slat[1][e+1]*w1;
    }
    sh4a[q][tt] = l00 + l01;
    sh4b[q][tt] = l10 + l11;
  }
  __syncthreads();
  float xh30 = -3e38f, xh31 = -3e38f;
  if (t < 128){
    float d30 = (sh4a[0][t] + sh4a[1][t]) + (sh4a[2][t] + sh4a[3][t]);
    float d31 = (sh4b[0][t] + sh4b[1][t]) + (sh4b[2][t] + sh4b[3][t]);
    xh30 = -(ln0 - 2.f*d30 + w3norm[t]) * (1.f/128.f);
    xh31 = -(ln1 - 2.f*d31 + w3norm[t]) * (1.f/128.f);
  }
  float m30, s30, m31, s31; int idx0, idx1;
  blockSoftmaxMSI2(xh30, xh31, tt, t < 128, rr[3], ri, t,
                   m30, s30, idx0, m31, s31, idx1);
  if (t < 128){
    sp[0][t] = __expf(xh30 - m30) / s30;
    sp[1][t] = __expf(xh31 - m31) / s31;
  }
  float dsq0 = in0 - 2.f*sd1[0][idx0] + c1norm[idx0];
  float dsq1 = in1 - 2.f*sd1[1][idx1] + c1norm[idx1];

  // -- stage 5: di[j] = sum_g simg[g]*W2[g][idx*JP+j]; quad-packed, dual idx
  {
    const unsigned short* Wb0 = W2 + (size_t)idx0 * JP_ + 4*ll;
    const unsigned short* Wb1 = W2 + (size_t)idx1 * JP_ + 4*ll;
    float p00=0,p01=0,p02=0,p03=0, p10=0,p11=0,p12=0,p13=0;
    int g0 = gq * 32;
    #pragma unroll 4
    for (int g = g0; g < g0 + 32; g++){
      uint2 w0 = *(const uint2*)(Wb0 + (size_t)g*KKP_);
      uint2 w1 = *(const uint2*)(Wb1 + (size_t)g*KKP_);
      float sv0 = simg[0][g], sv1 = simg[1][g];
      p00 += sv0 * __uint_as_float(w0.x << 16);
      p01 += sv0 * __uint_as_float(w0.x & 0xffff0000u);
      p02 += sv0 * __uint_as_float(w0.y << 16);
      p03 += sv0 * __uint_as_float(w0.y & 0xffff0000u);
      p10 += sv1 * __uint_as_float(w1.x << 16);
      p11 += sv1 * __uint_as_float(w1.x & 0xffff0000u);
      p12 += sv1 * __uint_as_float(w1.y << 16);
      p13 += sv1 * __uint_as_float(w1.y & 0xffff0000u);
    }
    float4 st0 = {p00,p01,p02,p03};
    float4 st1 = {p10,p11,p12,p13};
    *(float4*)&sh16a[gq][4*ll] = st0;
    *(float4*)&sh16b[gq][4*ll] = st1;
  }
  if (wvid < 2){
    int ib = wvid ? idx1 : idx0;
    const float* si = simg[wvid];
    const unsigned short* Wb8 = W2 + (size_t)ib * JP_ + 128;
    float s = 0.f;
    #pragma unroll
    for (int m = 0; m < 8; m++){
      int g = lane + 64*m;
      s += si[g] * bf2f(Wb8[(size_t)g * KKP_]);
    }
    #pragma unroll
    for (int off = 32; off > 0; off >>= 1) s += __shfl_down(s, off);
    if (lane == 0) xtra[wvid] = s;
  }
  __syncthreads();
  float xh20 = -3e38f, xh21 = -3e38f;
  if (t < J_){
    float di0, di1;
    if (t < 128){
      di0 = 0.f; di1 = 0.f;
      #pragma unroll
      for (int i = 0; i < 16; i++){ di0 += sh16a[i][t]; di1 += sh16b[i][t]; }
    } else { di0 = xtra[0]; di1 = xtra[1]; }
    int nb0 = idx0*J_ + t, nb1 = idx1*J_ + t;
    xh20 = -(dsq0 - 2.f*(di0 - cross[nb0]) + sq2[nb0]) * (1.f/512.f);
    xh21 = -(dsq1 - 2.f*(di1 - cross[nb1]) + sq2[nb1]) * (1.f/512.f);
  }
  float m20, s20, m21, s21;
  blockSoftmaxMS2(xh20, xh21, t < J_, rr[4], t, m20, s20, m21, s21);
  if (t < J_){
    sqv[0][t] = __expf(xh20 - m20) / s20;
    sqv[1][t] = __expf(xh21 - m21) / s21;
  }
  __syncthreads();

  // -- stage 6: lat2[e=tt] = sum_j xp2[j]*wrec2[j][e] (shared weights)
  {
    float lv0 = 0.f, lv1 = 0.f;
    int j0 = (q == 0) ? 0 : (q*32 + 1);
    int j1 = q*32 + 33;
    for (int j = j0; j < j1; j++){
      float w = wrec2[j*E2_ + tt];
      lv0 += sqv[0][j]*w; lv1 += sqv[1][j]*w;
    }
    sh4a[q][tt] = lv0;
    sh4b[q][tt] = lv1;
  }
  __syncthreads();
  float l20 = (sh4a[0][tt] + sh4a[1][tt]) + (sh4a[2][tt] + sh4a[3][tt]);
  float l21 = (sh4b[0][tt] + sh4b[1][tt]) + (sh4b[2][tt] + sh4b[3][tt]);
  if (q == 0){ slat[0][tt] = l20; slat[1][tt] = l21; }
  float n20, n21;
  blockSum2((q == 0) ? l20*l20 : 0.f, (q == 0) ? l21*l21 : 0.f, rr[5], t, n20, n21);

  // -- stage 7: d6[j=tt] = sum_e lat2[e]*wrec2T[e][j] (shared weights)
  {
    float l00=0,l01=0, l10=0,l11=0;
    int e0 = q * 32;
    const float* rT = wrec2T + tt;
    for (int e = e0; e < e0 + 32; e += 2){
      float w0 = rT[(e  )*J_];
      float w1 = rT[(e+1)*J_];
      l00 += slat[0][e]*w0; l01 += slat[0][e+1]*w1;
      l10 += slat[1][e]*w0; l11 += slat[1][e+1]*w1;
    }
    sh4a[q][tt] = l00 + l01;
    sh4b[q][tt] = l10 + l11;
  }
  if (wvid < 2){
    const float* sl = slat[wvid];
    float s = sl[lane]*wrec2T[lane*J_ + 128] + sl[lane+64]*wrec2T[(lane+64)*J_ + 128];
    #pragma unroll
    for (int off = 32; off > 0; off >>= 1) s += __shfl_down(s, off);
    if (lane == 0) xtra[2 + wvid] = s;
  }
  __syncthreads();
  float xh60 = -3e38f, xh61 = -3e38f;
  if (t < J_){
    float d60, d61;
    if (t < 128){
      d60 = (sh4a[0][t] + sh4a[1][t]) + (sh4a[2][t] + sh4a[3][t]);
      d61 = (sh4b[0][t] + sh4b[1][t]) + (sh4b[2][t] + sh4b[3][t]);
    } else { d60 = xtra[2]; d61 = xtra[3]; }
    xh60 = -(n20 - 2.f*d60 + w6norm[t]) * (1.f/128.f);
    xh61 = -(n21 - 2.f*d61 + w6norm[t]) * (1.f/128.f);
  }
  float m60, s60, m61, s61;
  blockSoftmaxMS2(xh60, xh61, t < J_, rr[6], t, m60, s60, m61, s61);
  if (t < J_){
    sqv[0][t] = __expf(xh60 - m60) / s60;
    sqv[1][t] = __expf(xh61 - m61) / s61;
  }
  __syncthreads();

  // -- R fill, packed uint (2 bf16 per store), both rows
  unsigned int* R0 = (unsigned int*)(Rm + (size_t)b0 * KKP_);
  unsigned int* R1 = (unsigned int*)(Rm + (size_t)b1 * KKP_);
  int k = t / 66;                          // JP/2 = 66
  int j2 = t - k*66;
  for (int kk2 = t; kk2 < KKP_/2; kk2 += 512){
    float v00 = 0.f, v01 = 0.f, v10 = 0.f, v11 = 0.f;
    if (kk2 < KK2_/2){
      int j = 2*j2;
      float pk0 = sp[0][k], pk1 = sp[1][k];
      bool jo0 = (j < J_), jo1 = (j+1 < J_);
      v00 = jo0 ? pk0 * sqv[0][j]   : 0.f;
      v01 = jo1 ? pk0 * sqv[0][j+1] : 0.f;
      v10 = jo0 ? pk1 * sqv[1][j]   : 0.f;
      v11 = jo1 ? pk1 * sqv[1][j+1] : 0.f;
    } else if (kk2 < KKE2_/2){
      int e = 2*(kk2 - KK2_/2);
      v00 = sp[0][e]; v01 = sp[0][e+1];
      v10 = sp[1][e]; v11 = sp[1][e+1];
    }
    R0[kk2] = (unsigned int)f2bf(v00) | ((unsigned int)f2bf(v01) << 16);
    R1[kk2] = (unsigned int)f2bf(v10) | ((unsigned int)f2bf(v11) << 16);
    j2 += 50;                              // 512 mod 66
    if (j2 >= 66){ j2 -= 66; k += 8; } else k += 7;
  }
}

// ---- big einsum as bf16 NT GEMM, split-K, BK=64, dbuf, XOR-swizzled LDS:
// part[z][b][g] = sum_{kk in chunk z} R[b,kk]*W2[g,kk]   (part stored bf16)
__global__ __launch_bounds__(256) void gemm_kernel(
    const unsigned short* __restrict__ Rm, const unsigned short* __restrict__ W2,
    unsigned short* __restrict__ part){
  // per buffer: A[128][64]bf16 (16KB=4096u) + B same; 2 buffers = 64 KB
  __shared__ __align__(16) unsigned int lds[16384];
  auto lds3 = (__attribute__((address_space(3))) unsigned int*)lds;
  int tid = threadIdx.x;
  int l = tid & 63;
  int wv = tid >> 6;
  int wr = (wv >> 1) * 64, wc = (wv & 1) * 64;
  int b0 = blockIdx.y * 128, g0 = blockIdx.x * 128;
  size_t kkbase = (size_t)blockIdx.z * KCHUNK;

  // staging: thread covers row (tid>>3) [+32 per call], 16B chunk (tid&7),
  // with global chunk pre-swizzled so swizzled-read is conflict-free (rule #21)
  int srow = tid >> 3;                     // [0,32)
  int cswz = (tid & 7) ^ (srow & 7);       // row&7 invariant across +32-row calls
  const unsigned short* ga = Rm + (size_t)(b0 + srow)*KKP_ + kkbase + cswz*8;
  const unsigned short* gb = W2 + (size_t)(g0 + srow)*KKP_ + kkbase + cswz*8;

  int lrow = l & 15, lh = l >> 4, p7 = l & 7;

  f32x4 zero4 = {0.f, 0.f, 0.f, 0.f};
  f32x4 acc[4][4];
  #pragma unroll
  for (int mi = 0; mi < 4; mi++)
    #pragma unroll
    for (int ni = 0; ni < 4; ni++) acc[mi][ni] = zero4;

  auto STAGE = [&](int bb){
    unsigned int base = bb * 8192;
    #pragma unroll
    for (int c = 0; c < 4; c++){
      GLOAD16(ga + (size_t)c*32*KKP_, lds3 + base + c*1024 + wv*256);
      GLOAD16(gb + (size_t)c*32*KKP_, lds3 + base + 4096 + c*1024 + wv*256);
    }
    ga += BK_; gb += BK_;
  };

  STAGE(0);                                // prologue: tile 0 -> buffer 0
  int cur = 0;
  for (int s = 0; s < KSTEPS; s++){
    __syncthreads();                       // vmcnt drain: buf[cur] ready
    if (s + 1 < KSTEPS) STAGE(cur ^ 1);
    const unsigned int* lA = lds + cur*8192;
    const unsigned int* lB = lA + 4096;
    #pragma unroll
    for (int s2 = 0; s2 < 2; s2++){
      int slot = ((s2 << 2) + lh) ^ p7;    // un-swizzle on read
      short8 af[4], bfv[4];
      #pragma unroll
      for (int mi = 0; mi < 4; mi++)
        af[mi] = *(const short8*)(lA + (wr + mi*16 + lrow)*32 + slot*4);
      #pragma unroll
      for (int ni = 0; ni < 4; ni++)
        bfv[ni] = *(const short8*)(lB + (wc + ni*16 + lrow)*32 + slot*4);
      #pragma unroll
      for (int mi = 0; mi < 4; mi++)
        #pragma unroll
        for (int ni = 0; ni < 4; ni++)
          acc[mi][ni] = __builtin_amdgcn_mfma_f32_16x16x32_bf16(af[mi], bfv[ni], acc[mi][ni], 0, 0, 0);
    }
    cur ^= 1;
  }

  unsigned short* P = part + ((size_t)blockIdx.z * B_ + b0) * G_ + g0;
  int rh = (l >> 4) << 2, cl = l & 15;
  #pragma unroll
  for (int mi = 0; mi < 4; mi++)
    #pragma unroll
    for (int ni = 0; ni < 4; ni++)
      #pragma unroll
      for (int r = 0; r < 4; r++){
        int row = wr + mi*16 + rh + r;
        int col = wc + ni*16 + cl;
        P[(size_t)row*G_ + col] = f2bf(acc[mi][ni][r]);
      }
}

// ---- loss[b] = mean_g ( (sum_z part_bf16[z][b][g]) - img[b][g] )^2
__global__ __launch_bounds__(128) void loss_kernel(
    const float* __restrict__ img, const unsigned short* __restrict__ part,
    float* __restrict__ out){
  __shared__ float redf[2];
  int t = threadIdx.x, b = blockIdx.x;
  // each thread owns 4 consecutive g (t*4), summing 16 bf16 planes
  float x0 = 0.f, x1 = 0.f, x2 = 0.f, x3 = 0.f;
  #pragma unroll
  for (int z = 0; z < SPLITS; z++){
    const unsigned short* pr = part + ((size_t)z*B_ + b)*G_ + 4*t;
    uint2 v = *(const uint2*)pr;
    x0 += __uint_as_float(v.x << 16);
    x1 += __uint_as_float(v.x & 0xffff0000u);
    x2 += __uint_as_float(v.y << 16);
    x3 += __uint_as_float(v.y & 0xffff0000u);
  }
  float4 iv = *(const float4*)(img + (size_t)b*G_ + 4*t);
  float d0 = x0 - iv.x, d1 = x1 - iv.y, d2 = x2 - iv.z, d3 = x3 - iv.w;
  float acc = (d0*d0 + d1*d1) + (d2*d2 + d3*d3);
  #pragma unroll
  for (int off = 32; off > 0; off >>= 1) acc += __shfl_down(acc, off);
  __syncthreads();
  if ((t & 63) == 0) redf[t >> 6] = acc;
  __syncthreads();
  if (t == 0) out[b] = (redf[0] + redf[1]) * (1.f/512.f);
}

extern "C" void kernel_launch(void* const* d_in, const int* in_sizes, int n_in,
                              void* d_out, int out_size, void* d_ws, size_t ws_size,
                              hipStream_t stream){
  (void)in_sizes; (void)n_in; (void)out_size; (void)ws_size;
  const float* img   = (const float*)d_in[0];
  const float* wimg  = (const float*)d_in[1];
  const float* wrec  = (const float*)d_in[2];
  const float* wrec2 = (const float*)d_in[3];
  const float* wimg2 = (const float*)d_in[4];
  float* out = (float*)d_out;

  char* ws = (char*)d_ws;
  size_t off = 0;
  auto alloc = [&](size_t bytes) -> void* {
    void* p = ws + off;
    off += (bytes + 255) & ~(size_t)255;
    return p;
  };
  unsigned short* W2   = (unsigned short*)alloc((size_t)G_ * KKP_ * 2);
  unsigned short* Rm   = (unsigned short*)alloc((size_t)B_ * KKP_ * 2);
  unsigned short* part = (unsigned short*)alloc((size_t)SPLITS * B_ * G_ * 2);
  float* sqp    = (float*)alloc((size_t)GS_ * KK_ * 4);
  float* crp    = (float*)alloc((size_t)GS_ * KK_ * 4);
  float* sq2    = (float*)alloc((size_t)KK_ * 4);
  float* cross  = (float*)alloc((size_t)KK_ * 4);
  float* c1norm = (float*)alloc(K_ * 4);
  float* w3norm = (float*)alloc(K_ * 4);
  float* w6norm = (float*)alloc(J_ * 4);
  float* wrecT  = (float*)alloc((size_t)K_ * E2_ * 4);
  float* wrec2T = (float*)alloc((size_t)J_ * E2_ * 4);

  norms_kernel<<<dim3(69), dim3(1024), 0, stream>>>(wimg, wrec, wrec2, c1norm, w3norm, w6norm, wrecT, wrec2T, W2);
  tables_part_kernel<<<dim3(129, GS_), dim3(128), 0, stream>>>(wimg2, wimg, sqp, crp, W2);
  tables_reduce_kernel<<<dim3(129), dim3(128), 0, stream>>>(sqp, crp, sq2, cross);
  encdec_kernel<<<dim3(512), dim3(512), 0, stream>>>(img, wimg, wrec, wrec2, wrecT, wrec2T, W2,
      c1norm, w3norm, w6norm, sq2, cross, Rm);
  gemm_kernel<<<dim3(4, 8, SPLITS), dim3(256), 0, stream>>>(Rm, W2, part);
  loss_kernel<<<dim3(1024), dim3(128), 0, stream>>>(img, part, out);
}